// Round 11
// baseline (947.164 us; speedup 1.0000x reference)
//
#include <hip/hip_runtime.h>
#include <hip/hip_bf16.h>

#define BB 16
#define TT 16

typedef short short8  __attribute__((ext_vector_type(8)));
typedef short short4v __attribute__((ext_vector_type(4)));
typedef float f32x4   __attribute__((ext_vector_type(4)));

__device__ __forceinline__ ushort f2bf(float f) {
    uint u = __float_as_uint(f);
    u += 0x7FFFu + ((u >> 16) & 1u);      // RTNE
    return (ushort)(u >> 16);
}
__device__ __forceinline__ float bf2f(ushort h) { return __uint_as_float(((uint)h) << 16); }
__device__ __forceinline__ float fast_sigmoid(float x) { return 1.0f / (1.0f + __expf(-x)); }
__device__ __forceinline__ float fast_tanh(float x) {
    float e = __expf(2.0f * x);
    return 1.0f - 2.0f / (e + 1.0f);
}
__device__ __forceinline__ short8 pack8(const float4 a, const float4 b) {
    short8 r;
    r[0]=(short)f2bf(a.x); r[1]=(short)f2bf(a.y); r[2]=(short)f2bf(a.z); r[3]=(short)f2bf(a.w);
    r[4]=(short)f2bf(b.x); r[5]=(short)f2bf(b.y); r[6]=(short)f2bf(b.z); r[7]=(short)f2bf(b.w);
    return r;
}

// One kernel packs ALL weight tensors into bf16 MFMA A-fragments.
__global__ __launch_bounds__(256)
void pack_all(const float* __restrict__ wg, const float* __restrict__ wc,
              const float* __restrict__ wo, const float* __restrict__ w1,
              const float* __restrict__ w2,
              ushort* __restrict__ wfX, ushort* __restrict__ wfGh,
              ushort* __restrict__ wfCh, ushort* __restrict__ wfO,
              ushort* __restrict__ wf1, ushort* __restrict__ wf2)
{
    const int gi = blockIdx.x * 256 + threadIdx.x;
    const int fi = gi >> 6, lane = gi & 63;
    if (fi >= 528) return;
    const float* src; ushort* dst;
    int CINfull, ci_base, cb_base, CBn, CBT, NT, lf;
    if (fi < 144)      { lf=fi;     src=wg; dst=wfX;  CINfull=128; ci_base=0;  cb_base=0; CBn=8; CBT=12; NT=9; }
    else if (fi < 216) { lf=fi-144; src=wc; dst=wfX;  CINfull=128; ci_base=0;  cb_base=8; CBn=4; CBT=12; NT=9; }
    else if (fi < 360) { lf=fi-216; src=wg; dst=wfGh; CINfull=128; ci_base=64; cb_base=0; CBn=8; CBT=8;  NT=9; }
    else if (fi < 432) { lf=fi-360; src=wc; dst=wfCh; CINfull=128; ci_base=64; cb_base=0; CBn=4; CBT=4;  NT=9; }
    else if (fi < 504) { lf=fi-432; src=wo; dst=wfO;  CINfull=64;  ci_base=0;  cb_base=0; CBn=4; CBT=4;  NT=9; }
    else if (fi < 512) { lf=fi-504; src=w1; dst=wf1;  CINfull=64;  ci_base=0;  cb_base=0; CBn=4; CBT=4;  NT=1; }
    else               { lf=fi-512; src=w2; dst=wf2;  CINfull=64;  ci_base=0;  cb_base=0; CBn=8; CBT=8;  NT=1; }
    const int KCp = 2;
    const int kc = lf % KCp;
    const int cb = (lf / KCp) % CBn;
    const int tap = lf / (KCp * CBn);
    const int co  = cb * 16 + (lane & 15);
    const int ci0 = ci_base + kc * 32 + (lane >> 4) * 8;
    short8 v;
    #pragma unroll
    for (int e = 0; e < 8; ++e)
        v[e] = (short)f2bf(src[((size_t)co * CINfull + ci0 + e) * NT + tap]);
    const size_t fo = ((size_t)(tap * CBT + cb_base + cb)) * KCp + kc;
    *(short8*)(dst + (fo * 64 + lane) * 8) = v;
}

// Merged x-transpose + x-conv: reads x fp32 NCHW directly, writes
// Axc[bt][pix][192] = bf16(convX(x_t)+bias). 4-row tiles, coalesced I/O.
// LDS (ushort idx): xb bf16-swz [0,13056) ; fraw fp32 [13056,38656) (64ch x 200f)
//   (overlay after conv: outb [13056,38656))  Total 77312 B.
__global__ __launch_bounds__(512)
void conv_x(const float* __restrict__ xall,
            const ushort* __restrict__ wfX,
            const float* __restrict__ b_gates,
            const float* __restrict__ b_can,
            ushort* __restrict__ axc)
{
    extern __shared__ ushort smem[];
    ushort* xb   = smem;
    float*  fraw = (float*)(smem + 13056);
    ushort* outb = smem + 13056;

    const int rt = blockIdx.x, bt = blockIdx.y;
    const int R  = rt * 4;
    const int tid = threadIdx.x;
    const int w = tid >> 6, lane = tid & 63, lr = lane & 15, lg = lane >> 4;
    const float* xs = xall + (size_t)bt * 65536;

    // stage fp32 rows R-1..R+4 (coalesced float4)
    for (int i = tid; i < 3072; i += 512) {
        const int ch = i / 48, rem = i - ch * 48;
        const int tr = rem >> 3, q = rem & 7;
        const int y = R - 1 + tr;
        if ((unsigned)y < 32u)
            *(float4*)(fraw + ch * 200 + tr * 32 + q * 4) =
                *(const float4*)(xs + (size_t)ch * 1024 + y * 32 + q * 4);
    }
    __syncthreads();

    // convert -> bf16 swizzled halo tile
    for (int i = tid; i < 1632; i += 512) {
        const int tr = i / 272, rem = i - tr * 272;
        const int hc = rem >> 3, c8 = rem & 7;
        const int y = R - 1 + tr, x = hc - 1;
        short8 v = (short8)0;
        if ((unsigned)y < 32u && (unsigned)x < 32u) {
            #pragma unroll
            for (int e = 0; e < 8; ++e)
                v[e] = (short)f2bf(fraw[(c8 * 8 + e) * 200 + tr * 32 + x]);
        }
        *(short8*)(xb + (tr * 34 + hc) * 64 + ((c8 ^ ((hc + 7) & 7)) << 3)) = v;
    }
    __syncthreads();

    const int cb0 = (w & 3) * 3;
    const int pf0 = (w >> 2) * 4;

    f32x4 acc[3][4];
    #pragma unroll
    for (int i = 0; i < 3; ++i)
        #pragma unroll
        for (int j = 0; j < 4; ++j) acc[i][j] = 0;

    #pragma unroll
    for (int tap = 0; tap < 9; ++tap) {
        const int ky = tap / 3, kx = tap - ky * 3;
        #pragma unroll
        for (int kc = 0; kc < 2; ++kc) {
            short8 a[3];
            #pragma unroll
            for (int i = 0; i < 3; ++i)
                a[i] = *(const short8*)(wfX + (size_t)(((tap * 12 + cb0 + i) * 2 + kc) * 512) + lane * 8);
            #pragma unroll
            for (int j = 0; j < 4; ++j) {
                const int px = (pf0 + j) * 16 + lr;
                const int tr = (px >> 5) + ky, hc = (px & 31) + kx;
                short8 bf = *(const short8*)(xb + (tr * 34 + hc) * 64 + (((kc * 4 + lg) ^ ((hc + 7) & 7)) << 3));
                #pragma unroll
                for (int i = 0; i < 3; ++i)
                    acc[i][j] = __builtin_amdgcn_mfma_f32_16x16x32_bf16(a[i], bf, acc[i][j], 0, 0, 0);
            }
        }
    }
    __syncthreads();     // xb/fraw reads complete; overlay outb

    #pragma unroll
    for (int i = 0; i < 3; ++i) {
        const int co0 = (cb0 + i) * 16 + lg * 4;
        const float* bsrc = (co0 < 128) ? (b_gates + co0) : (b_can + co0 - 128);
        const f32x4 b4 = *(const f32x4*)bsrc;
        #pragma unroll
        for (int j = 0; j < 4; ++j) {
            const int px = (pf0 + j) * 16 + lr;
            short4v s;
            #pragma unroll
            for (int r = 0; r < 4; ++r)
                s[r] = (short)f2bf(acc[i][j][r] + b4[r]);
            *(short4v*)(outb + px * 200 + co0) = s;
        }
    }
    __syncthreads();

    ushort* dst = axc + (((size_t)bt * 1024) + R * 32) * 192;
    for (int i = tid; i < 3072; i += 512) {
        const int px = i / 24, c = i - px * 24;
        *(short8*)(dst + (size_t)px * 192 + c * 8) = *(const short8*)(outb + px * 200 + c * 8);
    }
}

// ---- fused ConvGRU-ODE step: 1-row tiles, 512 blocks = 2 blocks/CU ----
// Weight-efficient wave maps: A: 1 cb/wave; B: balanced reset/update split.
__global__ __launch_bounds__(512, 4)
void fused_step(const ushort* __restrict__ axc,
                const float* __restrict__ h_in,
                const ushort* __restrict__ h_inb,
                float* __restrict__ h_out,
                ushort* __restrict__ h_outb,
                const ushort* __restrict__ wfO,
                const ushort* __restrict__ wfGh,
                const ushort* __restrict__ wfCh,
                const float* __restrict__ b_ode,
                const float* __restrict__ tsteps,
                const float* __restrict__ mask,
                int t)
{
    extern __shared__ ushort smem[];
    float*  smemf = (float*)smem;
    ushort* hbuf  = smem;                 // 7 rows
    ushort* obuf  = smem + 15232;         // 5 rows
    ushort* rhbuf = smem;                 // overlay: 3 rows
    float*  ubuf  = smemf + 3264;         // row R u, fp32
    float*  hode  = smemf + 13056;        // row R h_ode, fp32

    const int R = blockIdx.x, b = blockIdx.y;
    const int tid = threadIdx.x;
    const int w = tid >> 6, lane = tid & 63, lr = lane & 15, lg = lane >> 4;
    const int bti = b * TT + (TT - 1 - t);

    const ushort* hbb = h_inb + (size_t)b * 1026 * 64;
    const float*  hb  = h_in  + (size_t)b * 65536;
    const ushort* axb = axc + (size_t)bti * 1024 * 192;

    // ---- hoisted Gx/Cx acc-init loads (match phase-B/C wave maps) ----
    short4v gxr[2][2], cxr;
    {
        const bool lowW = (w < 4);
        const int cbR  = lowW ? w : (w - 4);
        const int cog0 = cbR * 16 + lg * 4;           // reset co (unit 0)
        const int cog1 = w * 16 + lg * 4;             // lowW: reset(=cog0) ; highW: update
        const int y0 = R - 1 + (lowW ? 0 : 1);
        const int y1 = lowW ? (R + 1) : R;
        #pragma unroll
        for (int j = 0; j < 2; ++j) {
            const int c = j * 16 + lr;
            short4v g0 = (short4v)0, g1 = (short4v)0;
            if ((unsigned)y0 < 32u)
                g0 = *(const short4v*)(axb + ((size_t)(y0 * 32 + c)) * 192 + cog0);
            if ((unsigned)y1 < 32u)
                g1 = *(const short4v*)(axb + ((size_t)(y1 * 32 + c)) * 192 + cog1);
            gxr[0][j] = g0;
            gxr[1][j] = g1;
        }
        const int cbC = w >> 1, fjC = w & 1;
        cxr = *(const short4v*)(axb + ((size_t)(R * 32 + fjC * 16 + lr)) * 192 + 128 + cbC * 16 + lg * 4);
    }

    // ---- stage: hbuf rows R-3..R+3 ; obuf halo cols + OOB rows zero ----
    for (int i = tid; i < 1904; i += 512) {
        const int tr = i / 272, rem = i - tr * 272;
        const int hc = rem >> 3;
        const int y  = R - 3 + tr;
        short8 v = (short8)0;
        if ((unsigned)y < 32u && hc != 0 && hc != 33)
            v = *(const short8*)(hbb + ((size_t)(y * 32 + hc)) * 64 + (rem & 7) * 8);
        *(short8*)(hbuf + (size_t)i * 8) = v;
    }
    for (int i = tid; i < 1360; i += 512) {
        const int tr = i / 272, rem = i - tr * 272;
        const int hc = rem >> 3;
        const int y  = R - 2 + tr;
        if (hc == 0 || hc == 33 || (unsigned)y >= 32u)
            *(short8*)(obuf + (size_t)i * 8) = (short8)0;
    }
    __syncthreads();

    // ---- phase A: h_ode rows R-2..R+2 ; wave = (cb = w&3, colhalf = w>>2), 5 rows ----
    {
        const int cb = w & 3, ph = w >> 2;
        const int c  = ph * 16 + lr;
        f32x4 accA[5];
        #pragma unroll
        for (int j = 0; j < 5; ++j) accA[j] = 0;

        #pragma unroll
        for (int tap = 0; tap < 9; ++tap) {
            const int ky = tap / 3, kx = tap - ky * 3;
            #pragma unroll
            for (int kc = 0; kc < 2; ++kc) {
                short8 a = *(const short8*)(wfO + (size_t)(((tap * 4 + cb) * 2 + kc) * 512) + lane * 8);
                const int hc = c + kx;
                const int sz = (((kc << 2) + lg) ^ ((hc + 7) & 7)) << 3;
                #pragma unroll
                for (int j = 0; j < 5; ++j) {
                    short8 bf = *(const short8*)(hbuf + ((j + ky) * 34 + hc) * 64 + sz);
                    accA[j] = __builtin_amdgcn_mfma_f32_16x16x32_bf16(a, bf, accA[j], 0, 0, 0);
                }
            }
        }
        const float dt = (t == 0) ? -0.01f : (tsteps[TT - 1 - t] - tsteps[TT - t]);
        const int co0 = cb * 16 + lg * 4;
        const f32x4 b4 = *(const f32x4*)(b_ode + co0);
        #pragma unroll
        for (int j = 0; j < 5; ++j) {
            const int y = R - 2 + j;
            if ((unsigned)y < 32u) {
                const f32x4 h4 = *(const f32x4*)(hb + ((size_t)(y * 32 + c)) * 64 + co0);
                f32x4 ho;
                #pragma unroll
                for (int r = 0; r < 4; ++r)
                    ho[r] = h4[r] + fast_tanh(accA[j][r] + b4[r]) * dt;
                short4v s;
                #pragma unroll
                for (int r = 0; r < 4; ++r) s[r] = (short)f2bf(ho[r]);
                *(short4v*)(obuf + (j * 34 + c + 1) * 64 + (((co0 >> 3) ^ (c & 7)) << 3) + (co0 & 7)) = s;
                if (j == 2)
                    *(f32x4*)(hode + c * 64 + (((co0 >> 2) ^ (c & 15)) << 2)) = ho;
            }
        }
    }
    __syncthreads();

    // rhbuf: zero halo cols + OOB rows (overlays dead hbuf)
    for (int i = tid; i < 816; i += 512) {
        const int tr = i / 272, rem = i - tr * 272;
        const int hc = rem >> 3;
        const int y  = R - 1 + tr;
        if (hc == 0 || hc == 33 || (unsigned)y >= 32u)
            *(short8*)(rhbuf + (size_t)i * 8) = (short8)0;
    }

    // ---- phase B: gates ; waves 0-3: reset cb=w rows {0,2} ; waves 4-7:
    //      reset cb=w-4 row 1  +  update cb=w row 1 ----
    {
        const bool lowW = (w < 4);
        const int cbR = lowW ? w : (w - 4);
        const int fq0 = lowW ? 0 : 1;         // unit0 row (reset)
        const int fq1 = lowW ? 2 : 1;         // unit1 row (lowW reset / highW update)
        f32x4 accB[2][2];
        #pragma unroll
        for (int i = 0; i < 2; ++i)
            #pragma unroll
            for (int j = 0; j < 2; ++j) {
                f32x4 g;
                #pragma unroll
                for (int r = 0; r < 4; ++r) g[r] = bf2f((ushort)gxr[i][j][r]);
                accB[i][j] = g;
            }

        #pragma unroll
        for (int tap = 0; tap < 9; ++tap) {
            const int ky = tap / 3, kx = tap - ky * 3;
            #pragma unroll
            for (int kc = 0; kc < 2; ++kc) {
                short8 a0 = *(const short8*)(wfGh + (size_t)(((tap * 8 + cbR) * 2 + kc) * 512) + lane * 8);
                short8 a1 = lowW ? a0
                    : *(const short8*)(wfGh + (size_t)(((tap * 8 + w) * 2 + kc) * 512) + lane * 8);
                #pragma unroll
                for (int j = 0; j < 2; ++j) {
                    const int hc = j * 16 + lr + kx;
                    const int sz = (((kc << 2) + lg) ^ ((hc + 7) & 7)) << 3;
                    short8 bf0 = *(const short8*)(obuf + ((fq0 + ky) * 34 + hc) * 64 + sz);
                    short8 bf1 = lowW ? *(const short8*)(obuf + ((fq1 + ky) * 34 + hc) * 64 + sz) : bf0;
                    accB[0][j] = __builtin_amdgcn_mfma_f32_16x16x32_bf16(a0, bf0, accB[0][j], 0, 0, 0);
                    accB[1][j] = __builtin_amdgcn_mfma_f32_16x16x32_bf16(a1, bf1, accB[1][j], 0, 0, 0);
                }
            }
        }
        const int cog0 = cbR * 16 + lg * 4;
        // unit0: reset row fq0
        {
            const int y = R - 1 + fq0;
            if ((unsigned)y < 32u) {
                #pragma unroll
                for (int j = 0; j < 2; ++j) {
                    const int c = j * 16 + lr;
                    const int key = (((cog0 >> 3) ^ (c & 7)) << 3) + (cog0 & 7);
                    short4v ho4 = *(const short4v*)(obuf + ((fq0 + 1) * 34 + c + 1) * 64 + key);
                    short4v s;
                    #pragma unroll
                    for (int r = 0; r < 4; ++r)
                        s[r] = (short)f2bf(fast_sigmoid(accB[0][j][r]) * bf2f((ushort)ho4[r]));
                    *(short4v*)(rhbuf + (fq0 * 34 + c + 1) * 64 + key) = s;
                }
            }
        }
        // unit1: lowW -> reset row 2 ; highW -> update row R
        if (lowW) {
            const int y = R + 1;
            if ((unsigned)y < 32u) {
                #pragma unroll
                for (int j = 0; j < 2; ++j) {
                    const int c = j * 16 + lr;
                    const int key = (((cog0 >> 3) ^ (c & 7)) << 3) + (cog0 & 7);
                    short4v ho4 = *(const short4v*)(obuf + (3 * 34 + c + 1) * 64 + key);
                    short4v s;
                    #pragma unroll
                    for (int r = 0; r < 4; ++r)
                        s[r] = (short)f2bf(fast_sigmoid(accB[1][j][r]) * bf2f((ushort)ho4[r]));
                    *(short4v*)(rhbuf + (2 * 34 + c + 1) * 64 + key) = s;
                }
            }
        } else {
            const int cu = (w - 4) * 16 + lg * 4;
            #pragma unroll
            for (int j = 0; j < 2; ++j) {
                const int c = j * 16 + lr;
                f32x4 u;
                #pragma unroll
                for (int r = 0; r < 4; ++r)
                    u[r] = fast_sigmoid(accB[1][j][r]);
                *(f32x4*)(ubuf + c * 64 + (((cu >> 2) ^ (c & 15)) << 2)) = u;
            }
        }
    }
    __syncthreads();

    // ---- phase C: cand row R ; wave = (cb = w>>1, colhalf = w&1) ; GRU update ----
    {
        const int cb = w >> 1, fj = w & 1;
        const int co0 = cb * 16 + lg * 4;
        const int c   = fj * 16 + lr;
        f32x4 accC;
        #pragma unroll
        for (int r = 0; r < 4; ++r) accC[r] = bf2f((ushort)cxr[r]);

        #pragma unroll
        for (int tap = 0; tap < 9; ++tap) {
            const int ky = tap / 3, kx = tap - ky * 3;
            #pragma unroll
            for (int kc = 0; kc < 2; ++kc) {
                short8 a = *(const short8*)(wfCh + (size_t)(((tap * 4 + cb) * 2 + kc) * 512) + lane * 8);
                const int hc = c + kx;
                short8 bf = *(const short8*)(rhbuf + (ky * 34 + hc) * 64 + ((((kc << 2) + lg) ^ ((hc + 7) & 7)) << 3));
                accC = __builtin_amdgcn_mfma_f32_16x16x32_bf16(a, bf, accC, 0, 0, 0);
            }
        }
        const float m = mask[b * TT + (TT - 1 - t)];
        const int sw = ((co0 >> 2) ^ (c & 15)) << 2;
        const f32x4 ho = *(const f32x4*)(hode + c * 64 + sw);
        const f32x4 u  = *(const f32x4*)(ubuf + c * 64 + sw);
        f32x4 o;
        short4v s;
        #pragma unroll
        for (int r = 0; r < 4; ++r) {
            const float cand = fast_tanh(accC[r]);
            o[r] = ho[r] + m * u[r] * (cand - ho[r]);
            s[r] = (short)f2bf(o[r]);
        }
        const int pix = R * 32 + c;
        *(f32x4*)(h_out + (size_t)b * 65536 + (size_t)pix * 64 + co0) = o;
        *(short4v*)(h_outb + ((size_t)b * 1026 + 1 + pix) * 64
                    + (((co0 >> 3) ^ (c & 7)) << 3) + (co0 & 7)) = s;
    }
}

// Head: z = relu(W1 h + b1); z2 = W2 z + b2; out NCHW (mean, |std|)
__global__ __launch_bounds__(256)
void head_mfma(const float* __restrict__ h,
               const ushort* __restrict__ w1f, const float* __restrict__ b1,
               const ushort* __restrict__ w2f, const float* __restrict__ b2,
               float* __restrict__ outp)
{
    __shared__ ushort hlds[64 * 64];
    __shared__ ushort zlds[64 * 64];
    const int blk = blockIdx.x, b = blk >> 4, pixb = (blk & 15) * 64;
    const int tid = threadIdx.x, wv = tid >> 6, lane = tid & 63, lr = lane & 15, lg = lane >> 4;
    const float* hb = h + ((size_t)b * 1024 + pixb) * 64;

    for (int idx = tid; idx < 64 * 8; idx += 256) {
        const int c = idx & 7, px = idx >> 3;
        const float4* p = (const float4*)(hb + (size_t)px * 64 + c * 8);
        *(short8*)(hlds + px * 64 + ((c ^ (px & 7)) << 3)) = pack8(p[0], p[1]);
    }
    __syncthreads();

    f32x4 acc1[4]; acc1[0]=0; acc1[1]=0; acc1[2]=0; acc1[3]=0;
    #pragma unroll
    for (int kc = 0; kc < 2; ++kc) {
        short8 a = *(const short8*)(w1f + (((size_t)wv * 2 + kc) * 64 + lane) * 8);
        #pragma unroll
        for (int p = 0; p < 4; ++p) {
            const int hp = p * 16 + lr;
            short8 bf = *(const short8*)(hlds + hp * 64 + (((kc * 4 + lg) ^ (hp & 7)) << 3));
            acc1[p] = __builtin_amdgcn_mfma_f32_16x16x32_bf16(a, bf, acc1[p], 0, 0, 0);
        }
    }
    {
        const int co0 = wv * 16 + lg * 4;
        const f32x4 b4 = *(const f32x4*)(b1 + co0);
        #pragma unroll
        for (int p = 0; p < 4; ++p) {
            const int px = p * 16 + lr;
            short4v s;
            #pragma unroll
            for (int r = 0; r < 4; ++r)
                s[r] = (short)f2bf(fmaxf(acc1[p][r] + b4[r], 0.0f));
            *(short4v*)(zlds + px * 64 + (((co0 >> 3) ^ (px & 7)) << 3) + (co0 & 7)) = s;
        }
    }
    __syncthreads();

    f32x4 acc2[2][4];
    #pragma unroll
    for (int gi = 0; gi < 2; ++gi)
        #pragma unroll
        for (int p = 0; p < 4; ++p) acc2[gi][p] = 0;
    #pragma unroll
    for (int kc = 0; kc < 2; ++kc) {
        short8 a0 = *(const short8*)(w2f + ((((size_t)wv * 2 + 0) * 2 + kc) * 64 + lane) * 8);
        short8 a1 = *(const short8*)(w2f + ((((size_t)wv * 2 + 1) * 2 + kc) * 64 + lane) * 8);
        #pragma unroll
        for (int p = 0; p < 4; ++p) {
            const int hp = p * 16 + lr;
            short8 bf = *(const short8*)(zlds + hp * 64 + (((kc * 4 + lg) ^ (hp & 7)) << 3));
            acc2[0][p] = __builtin_amdgcn_mfma_f32_16x16x32_bf16(a0, bf, acc2[0][p], 0, 0, 0);
            acc2[1][p] = __builtin_amdgcn_mfma_f32_16x16x32_bf16(a1, bf, acc2[1][p], 0, 0, 0);
        }
    }
    #pragma unroll
    for (int gi = 0; gi < 2; ++gi) {
        const int co0 = wv * 32 + gi * 16 + lg * 4;
        const f32x4 b4 = *(const f32x4*)(b2 + co0);
        #pragma unroll
        for (int p = 0; p < 4; ++p) {
            const int px = pixb + p * 16 + lr;
            #pragma unroll
            for (int r = 0; r < 4; ++r) {
                const int co = co0 + r;
                const float v = acc2[gi][p][r] + b4[r];
                if (co < 64)
                    outp[((size_t)b * 64 + co) * 1024 + px] = v;
                else
                    outp[(size_t)BB * 64 * 1024 + ((size_t)b * 64 + (co - 64)) * 1024 + px] = fabsf(v);
            }
        }
    }
}

extern "C" void kernel_launch(void* const* d_in, const int* in_sizes, int n_in,
                              void* d_out, int out_size, void* d_ws, size_t ws_size,
                              hipStream_t stream)
{
    const float* xall    = (const float*)d_in[0];
    const float* tsteps  = (const float*)d_in[1];
    const float* mask    = (const float*)d_in[2];
    const float* w_gates = (const float*)d_in[3];
    const float* b_gates = (const float*)d_in[4];
    const float* w_can   = (const float*)d_in[5];
    const float* b_can   = (const float*)d_in[6];
    const float* w_ode   = (const float*)d_in[7];
    const float* b_ode   = (const float*)d_in[8];
    const float* w_t1    = (const float*)d_in[9];
    const float* b_t1    = (const float*)d_in[10];
    const float* w_t2    = (const float*)d_in[11];
    const float* b_t2    = (const float*)d_in[12];
    float* out = (float*)d_out;

    float*  h0   = (float*)d_ws;
    float*  h1   = h0 + (size_t)BB * 65536;
    ushort* h0b  = (ushort*)(h1 + (size_t)BB * 65536);
    ushort* h1b  = h0b + (size_t)BB * 1026 * 64;
    ushort* axc  = h1b + (size_t)BB * 1026 * 64;
    ushort* wfX  = axc + (size_t)256 * 1024 * 192;
    ushort* wfGh = wfX  + (size_t)216 * 512;
    ushort* wfCh = wfGh + (size_t)144 * 512;
    ushort* wfO  = wfCh + (size_t)72 * 512;
    ushort* wf1  = wfO  + (size_t)72 * 512;
    ushort* wf2  = wf1  + (size_t)8 * 512;

    hipMemsetAsync(h0, 0, (size_t)BB * 65536 * sizeof(float), stream);
    hipMemsetAsync(h0b, 0, (size_t)BB * 1026 * 64 * 2 * sizeof(ushort), stream);

    pack_all<<<dim3(132), 256, 0, stream>>>(w_gates, w_can, w_ode, w_t1, w_t2,
                                            wfX, wfGh, wfCh, wfO, wf1, wf2);

    hipFuncSetAttribute(reinterpret_cast<const void*>(conv_x),
                        hipFuncAttributeMaxDynamicSharedMemorySize, 77312);
    conv_x<<<dim3(8, 256), 512, 77312, stream>>>(xall, wfX, b_gates, b_can, axc);

    hipFuncSetAttribute(reinterpret_cast<const void*>(fused_step),
                        hipFuncAttributeMaxDynamicSharedMemorySize, 60416);

    for (int t = 0; t < TT; ++t) {
        const float*  hin   = (t & 1) ? h1  : h0;
        float*        hout  = (t & 1) ? h0  : h1;
        const ushort* hinb  = (t & 1) ? h1b : h0b;
        ushort*       houtb = (t & 1) ? h0b : h1b;
        fused_step<<<dim3(32, BB), 512, 60416, stream>>>(axc, hin, hinb, hout, houtb,
                                                         wfO, wfGh, wfCh,
                                                         b_ode, tsteps, mask, t);
    }
    head_mfma<<<dim3(256), 256, 0, stream>>>(h0, wf1, b_t1, wf2, b_t2, out);
}

// Round 12
// 450.590 us; speedup vs baseline: 2.1020x; 2.1020x over previous
//
#include <hip/hip_runtime.h>
#include <hip/hip_bf16.h>

#define BB 16
#define TT 16

typedef short short8  __attribute__((ext_vector_type(8)));
typedef short short4v __attribute__((ext_vector_type(4)));
typedef float f32x4   __attribute__((ext_vector_type(4)));

__device__ __forceinline__ ushort f2bf(float f) {
    uint u = __float_as_uint(f);
    u += 0x7FFFu + ((u >> 16) & 1u);      // RTNE
    return (ushort)(u >> 16);
}
__device__ __forceinline__ float bf2f(ushort h) { return __uint_as_float(((uint)h) << 16); }
__device__ __forceinline__ float fast_sigmoid(float x) { return 1.0f / (1.0f + __expf(-x)); }
__device__ __forceinline__ float fast_tanh(float x) {
    float e = __expf(2.0f * x);
    return 1.0f - 2.0f / (e + 1.0f);
}
__device__ __forceinline__ short8 pack8(const float4 a, const float4 b) {
    short8 r;
    r[0]=(short)f2bf(a.x); r[1]=(short)f2bf(a.y); r[2]=(short)f2bf(a.z); r[3]=(short)f2bf(a.w);
    r[4]=(short)f2bf(b.x); r[5]=(short)f2bf(b.y); r[6]=(short)f2bf(b.z); r[7]=(short)f2bf(b.w);
    return r;
}

// One kernel packs ALL weight tensors into bf16 MFMA A-fragments.
__global__ __launch_bounds__(256)
void pack_all(const float* __restrict__ wg, const float* __restrict__ wc,
              const float* __restrict__ wo, const float* __restrict__ w1,
              const float* __restrict__ w2,
              ushort* __restrict__ wfX, ushort* __restrict__ wfGh,
              ushort* __restrict__ wfCh, ushort* __restrict__ wfO,
              ushort* __restrict__ wf1, ushort* __restrict__ wf2)
{
    const int gi = blockIdx.x * 256 + threadIdx.x;
    const int fi = gi >> 6, lane = gi & 63;
    if (fi >= 528) return;
    const float* src; ushort* dst;
    int CINfull, ci_base, cb_base, CBn, CBT, NT, lf;
    if (fi < 144)      { lf=fi;     src=wg; dst=wfX;  CINfull=128; ci_base=0;  cb_base=0; CBn=8; CBT=12; NT=9; }
    else if (fi < 216) { lf=fi-144; src=wc; dst=wfX;  CINfull=128; ci_base=0;  cb_base=8; CBn=4; CBT=12; NT=9; }
    else if (fi < 360) { lf=fi-216; src=wg; dst=wfGh; CINfull=128; ci_base=64; cb_base=0; CBn=8; CBT=8;  NT=9; }
    else if (fi < 432) { lf=fi-360; src=wc; dst=wfCh; CINfull=128; ci_base=64; cb_base=0; CBn=4; CBT=4;  NT=9; }
    else if (fi < 504) { lf=fi-432; src=wo; dst=wfO;  CINfull=64;  ci_base=0;  cb_base=0; CBn=4; CBT=4;  NT=9; }
    else if (fi < 512) { lf=fi-504; src=w1; dst=wf1;  CINfull=64;  ci_base=0;  cb_base=0; CBn=4; CBT=4;  NT=1; }
    else               { lf=fi-512; src=w2; dst=wf2;  CINfull=64;  ci_base=0;  cb_base=0; CBn=8; CBT=8;  NT=1; }
    const int KCp = 2;
    const int kc = lf % KCp;
    const int cb = (lf / KCp) % CBn;
    const int tap = lf / (KCp * CBn);
    const int co  = cb * 16 + (lane & 15);
    const int ci0 = ci_base + kc * 32 + (lane >> 4) * 8;
    short8 v;
    #pragma unroll
    for (int e = 0; e < 8; ++e)
        v[e] = (short)f2bf(src[((size_t)co * CINfull + ci0 + e) * NT + tap]);
    const size_t fo = ((size_t)(tap * CBT + cb_base + cb)) * KCp + kc;
    *(short8*)(dst + (fo * 64 + lane) * 8) = v;
}

// x (B,T,64,32,32) fp32 -> padded swizzled bf16 CL: [bt][1026 slots][64]
__global__ __launch_bounds__(256)
void x_transpose(const float* __restrict__ src, ushort* __restrict__ dst) {
    __shared__ float tile[64 * 256];
    const int bt = blockIdx.x, q = blockIdx.y, tid = threadIdx.x;
    const float* s = src + (size_t)bt * 64 * 1024 + q * 256;
    for (int i = tid; i < 64 * 256; i += 256)
        tile[i] = s[(size_t)(i >> 8) * 1024 + (i & 255)];
    __syncthreads();
    const int p = q * 256 + tid;
    ushort* d = dst + ((size_t)bt * 1026 + 1 + p) * 64;
    #pragma unroll
    for (int c8 = 0; c8 < 8; ++c8) {
        short8 v;
        #pragma unroll
        for (int e = 0; e < 8; ++e) v[e] = (short)f2bf(tile[(c8 * 8 + e) * 256 + tid]);
        *(short8*)(d + ((c8 ^ (p & 7)) << 3)) = v;
    }
    if (q == 0 && tid < 8)
        *(short8*)(dst + (size_t)bt * 1026 * 64 + tid * 8) = (short8)0;
    if (q == 3 && tid < 8)
        *(short8*)(dst + ((size_t)bt * 1026 + 1025) * 64 + tid * 8) = (short8)0;
}

// Precompute Axc[bt][pix][192] = bf16(convX(x_t)+bias). 4-row tiles, coalesced I/O.
__global__ __launch_bounds__(512)
void conv_x192(const ushort* __restrict__ x_cl,
               const ushort* __restrict__ wfX,
               const float* __restrict__ b_gates,
               const float* __restrict__ b_can,
               ushort* __restrict__ axc)
{
    __shared__ ushort sbuf[25600];
    const int rt = blockIdx.x, bt = blockIdx.y;
    const int R  = rt * 4;
    const int tid = threadIdx.x;
    const int w = tid >> 6, lane = tid & 63, lr = lane & 15, lg = lane >> 4;
    const ushort* xbb = x_cl + (size_t)bt * 1026 * 64;

    for (int i = tid; i < 1632; i += 512) {
        const int tr = i / 272, rem = i - tr * 272;
        const int hc = rem >> 3;
        const int y  = R - 1 + tr;
        short8 v = (short8)0;
        if ((unsigned)y < 32u && hc != 0 && hc != 33)
            v = *(const short8*)(xbb + ((size_t)(y * 32 + hc)) * 64 + (rem & 7) * 8);
        *(short8*)(sbuf + (size_t)i * 8) = v;
    }
    __syncthreads();

    const int cb0 = (w & 3) * 3;
    const int pf0 = (w >> 2) * 4;

    f32x4 acc[3][4];
    #pragma unroll
    for (int i = 0; i < 3; ++i)
        #pragma unroll
        for (int j = 0; j < 4; ++j) acc[i][j] = 0;

    #pragma unroll
    for (int tap = 0; tap < 9; ++tap) {
        const int ky = tap / 3, kx = tap - ky * 3;
        #pragma unroll
        for (int kc = 0; kc < 2; ++kc) {
            short8 a[3];
            #pragma unroll
            for (int i = 0; i < 3; ++i)
                a[i] = *(const short8*)(wfX + (size_t)(((tap * 12 + cb0 + i) * 2 + kc) * 512) + lane * 8);
            #pragma unroll
            for (int j = 0; j < 4; ++j) {
                const int px = (pf0 + j) * 16 + lr;
                const int tr = (px >> 5) + ky, hc = (px & 31) + kx;
                short8 bf = *(const short8*)(sbuf + (tr * 34 + hc) * 64 + (((kc * 4 + lg) ^ ((hc + 7) & 7)) << 3));
                #pragma unroll
                for (int i = 0; i < 3; ++i)
                    acc[i][j] = __builtin_amdgcn_mfma_f32_16x16x32_bf16(a[i], bf, acc[i][j], 0, 0, 0);
            }
        }
    }
    __syncthreads();

    #pragma unroll
    for (int i = 0; i < 3; ++i) {
        const int co0 = (cb0 + i) * 16 + lg * 4;
        const float* bsrc = (co0 < 128) ? (b_gates + co0) : (b_can + co0 - 128);
        const f32x4 b4 = *(const f32x4*)bsrc;
        #pragma unroll
        for (int j = 0; j < 4; ++j) {
            const int px = (pf0 + j) * 16 + lr;
            short4v s;
            #pragma unroll
            for (int r = 0; r < 4; ++r)
                s[r] = (short)f2bf(acc[i][j][r] + b4[r]);
            *(short4v*)(sbuf + px * 200 + co0) = s;
        }
    }
    __syncthreads();

    ushort* dst = axc + (((size_t)bt * 1024) + R * 32) * 192;
    for (int i = tid; i < 3072; i += 512) {
        const int px = i / 24, c = i - px * 24;
        *(short8*)(dst + (size_t)px * 192 + c * 8) = *(const short8*)(sbuf + px * 200 + c * 8);
    }
}

// ---- fused ConvGRU-ODE step (R7-proven): 2-row tiles, 256 blocks, 512 thr ----
// LDS (ushort idx): hbuf [0,17408) 8x34x128B ; obuf [17408,30464) 6x34x128B
//   overlay after A: rhbuf [0,8704) ; ubuf f32 @byte 17408 ; hode f32 @byte 60928.
__global__ __launch_bounds__(512, 1)
void fused_step(const ushort* __restrict__ axc,
                const float* __restrict__ h_in,
                const ushort* __restrict__ h_inb,
                float* __restrict__ h_out,
                ushort* __restrict__ h_outb,
                const ushort* __restrict__ wfO,
                const ushort* __restrict__ wfGh,
                const ushort* __restrict__ wfCh,
                const float* __restrict__ b_ode,
                const float* __restrict__ tsteps,
                const float* __restrict__ mask,
                int t)
{
    extern __shared__ ushort smem[];
    float*  smemf = (float*)smem;
    ushort* hbuf  = smem;
    ushort* obuf  = smem + 17408;
    ushort* rhbuf = smem;
    float*  ubuf  = smemf + 4352;
    float*  hode  = smemf + 15232;

    const int rt = blockIdx.x, b = blockIdx.y;
    const int R  = rt * 2;
    const int tid = threadIdx.x;
    const int w = tid >> 6, lane = tid & 63, lr = lane & 15, lg = lane >> 4;
    const int bti = b * TT + (TT - 1 - t);

    const ushort* hbb = h_inb + (size_t)b * 1026 * 64;
    const float*  hb  = h_in  + (size_t)b * 65536;
    const ushort* axb = axc + (size_t)bti * 1024 * 192;

    // ---- hoisted Gx/Cx acc-init loads ----
    short4v gxr[2][4], cxr[2];
    {
        const int cq = w & 3, ph = w >> 2;
        #pragma unroll
        for (int i = 0; i < 2; ++i) {
            const int cog0 = (2 * cq + i) * 16 + lg * 4;
            #pragma unroll
            for (int j = 0; j < 4; ++j) {
                const int f = 4 * ph + j;
                const int y = R - 1 + (f >> 1);
                const int c = (f & 1) * 16 + lr;
                short4v g = (short4v)0;
                if ((unsigned)y < 32u)
                    g = *(const short4v*)(axb + ((size_t)(y * 32 + c)) * 192 + cog0);
                gxr[i][j] = g;
            }
        }
        const int cf = w & 3, ph2 = w >> 2;
        const int co0 = cf * 16 + lg * 4;
        #pragma unroll
        for (int j = 0; j < 2; ++j) {
            const int c = j * 16 + lr;
            const int pix = (R + (ph2 & 1)) * 32 + c;
            cxr[j] = *(const short4v*)(axb + (size_t)pix * 192 + 128 + co0);
        }
    }

    // ---- stage: hbuf rows R-3..R+4 ; obuf halo cols + OOB rows zero ----
    for (int i = tid; i < 2176; i += 512) {
        const int tr = i / 272, rem = i - tr * 272;
        const int hc = rem >> 3;
        const int y  = R - 3 + tr;
        short8 v = (short8)0;
        if ((unsigned)y < 32u && hc != 0 && hc != 33)
            v = *(const short8*)(hbb + ((size_t)(y * 32 + hc)) * 64 + (rem & 7) * 8);
        *(short8*)(hbuf + (size_t)i * 8) = v;
    }
    for (int i = tid; i < 1632; i += 512) {
        const int tr = i / 272, rem = i - tr * 272;
        const int hc = rem >> 3;
        const int y  = R - 2 + tr;
        if (hc == 0 || hc == 33 || (unsigned)y >= 32u)
            *(short8*)(obuf + (size_t)i * 8) = (short8)0;
    }
    __syncthreads();

    // ---- phase A: h_ode rows R-2..R+3 (K=64 over hbuf) ----
    {
        const int cb0 = (w & 1) * 2;
        const int pxg = w >> 1;
        f32x4 accA[2][3];
        #pragma unroll
        for (int i = 0; i < 2; ++i)
            #pragma unroll
            for (int j = 0; j < 3; ++j) accA[i][j] = 0;

        #pragma unroll
        for (int tap = 0; tap < 9; ++tap) {
            const int ky = tap / 3, kx = tap - ky * 3;
            #pragma unroll
            for (int kc = 0; kc < 2; ++kc) {
                short8 a0 = *(const short8*)(wfO + (size_t)(((tap * 4 + cb0 + 0) * 2 + kc) * 512) + lane * 8);
                short8 a1 = *(const short8*)(wfO + (size_t)(((tap * 4 + cb0 + 1) * 2 + kc) * 512) + lane * 8);
                #pragma unroll
                for (int j = 0; j < 3; ++j) {
                    const int p  = (3 * pxg + j) * 16 + lr;
                    const int tr = (p >> 5) + ky, hc = (p & 31) + kx;
                    short8 bf = *(const short8*)(hbuf + (tr * 34 + hc) * 64 + ((((kc << 2) + lg) ^ ((hc + 7) & 7)) << 3));
                    accA[0][j] = __builtin_amdgcn_mfma_f32_16x16x32_bf16(a0, bf, accA[0][j], 0, 0, 0);
                    accA[1][j] = __builtin_amdgcn_mfma_f32_16x16x32_bf16(a1, bf, accA[1][j], 0, 0, 0);
                }
            }
        }
        const float dt = (t == 0) ? -0.01f : (tsteps[TT - 1 - t] - tsteps[TT - t]);
        #pragma unroll
        for (int i = 0; i < 2; ++i) {
            #pragma unroll
            for (int j = 0; j < 3; ++j) {
                const int co0 = (cb0 + i) * 16 + lg * 4;
                const int p = (3 * pxg + j) * 16 + lr;
                const int orow = p >> 5, c = p & 31;
                const int y = R - 2 + orow;
                if ((unsigned)y < 32u) {
                    const f32x4 h4 = *(const f32x4*)(hb + ((size_t)(y * 32 + c)) * 64 + co0);
                    const f32x4 b4 = *(const f32x4*)(b_ode + co0);
                    f32x4 ho;
                    #pragma unroll
                    for (int r = 0; r < 4; ++r)
                        ho[r] = h4[r] + fast_tanh(accA[i][j][r] + b4[r]) * dt;
                    short4v s;
                    #pragma unroll
                    for (int r = 0; r < 4; ++r) s[r] = (short)f2bf(ho[r]);
                    *(short4v*)(obuf + (orow * 34 + c + 1) * 64 + (((co0 >> 3) ^ (c & 7)) << 3) + (co0 & 7)) = s;
                    if ((unsigned)(y - R) < 2u)
                        *(f32x4*)(hode + ((y - R) * 32 + c) * 64 + (((co0 >> 2) ^ (c & 15)) << 2)) = ho;
                }
            }
        }
    }
    __syncthreads();

    // rhbuf: zero halo cols + OOB rows (overlays dead hbuf)
    for (int i = tid; i < 1088; i += 512) {
        const int tr = i / 272, rem = i - tr * 272;
        const int hc = rem >> 3;
        const int y  = R - 1 + tr;
        if (hc == 0 || hc == 33 || (unsigned)y >= 32u)
            *(short8*)(rhbuf + (size_t)i * 8) = (short8)0;
    }

    // ---- phase B: gates rows R-1..R+2 (K=64 over obuf, acc init from Gx) ----
    {
        const int cq = w & 3, ph = w >> 2;
        f32x4 accB[2][4];
        #pragma unroll
        for (int i = 0; i < 2; ++i)
            #pragma unroll
            for (int j = 0; j < 4; ++j) {
                f32x4 g;
                #pragma unroll
                for (int r = 0; r < 4; ++r) g[r] = bf2f((ushort)gxr[i][j][r]);
                accB[i][j] = g;
            }

        #pragma unroll
        for (int tap = 0; tap < 9; ++tap) {
            const int ky = tap / 3, kx = tap - ky * 3;
            #pragma unroll
            for (int kc = 0; kc < 2; ++kc) {
                short8 a0 = *(const short8*)(wfGh + (size_t)(((tap * 8 + 2 * cq + 0) * 2 + kc) * 512) + lane * 8);
                short8 a1 = *(const short8*)(wfGh + (size_t)(((tap * 8 + 2 * cq + 1) * 2 + kc) * 512) + lane * 8);
                #pragma unroll
                for (int j = 0; j < 4; ++j) {
                    const int f  = 4 * ph + j;
                    const int tr = (f >> 1) + ky;
                    const int hc = (f & 1) * 16 + lr + kx;
                    short8 bf = *(const short8*)(obuf + (tr * 34 + hc) * 64 + ((((kc << 2) + lg) ^ ((hc + 7) & 7)) << 3));
                    accB[0][j] = __builtin_amdgcn_mfma_f32_16x16x32_bf16(a0, bf, accB[0][j], 0, 0, 0);
                    accB[1][j] = __builtin_amdgcn_mfma_f32_16x16x32_bf16(a1, bf, accB[1][j], 0, 0, 0);
                }
            }
        }
        #pragma unroll
        for (int i = 0; i < 2; ++i) {
            const int cog = (2 * cq + i) * 16 + lg * 4;
            #pragma unroll
            for (int j = 0; j < 4; ++j) {
                const int f = 4 * ph + j;
                const int y = R - 1 + (f >> 1);
                const int c = (f & 1) * 16 + lr;
                if (cq < 2) {
                    if ((unsigned)y < 32u) {
                        const int tro = (f >> 1) + 1;
                        const int key = (((cog >> 3) ^ (c & 7)) << 3) + (cog & 7);
                        short4v ho4 = *(const short4v*)(obuf + (tro * 34 + c + 1) * 64 + key);
                        short4v s;
                        #pragma unroll
                        for (int r = 0; r < 4; ++r)
                            s[r] = (short)f2bf(fast_sigmoid(accB[i][j][r]) * bf2f((ushort)ho4[r]));
                        *(short4v*)(rhbuf + ((f >> 1) * 34 + c + 1) * 64 + key) = s;
                    }
                } else if ((unsigned)(y - R) < 2u) {
                    const int cu = cog - 64;
                    f32x4 u;
                    #pragma unroll
                    for (int r = 0; r < 4; ++r)
                        u[r] = fast_sigmoid(accB[i][j][r]);
                    *(f32x4*)(ubuf + ((y - R) * 32 + c) * 64 + (((cu >> 2) ^ (c & 15)) << 2)) = u;
                }
            }
        }
    }
    __syncthreads();

    // ---- phase C: cand rows R..R+1 (K=64 over rhbuf, acc init from Cx) ; GRU update ----
    {
        const int cf = w & 3, ph2 = w >> 2;
        const int co0 = cf * 16 + lg * 4;
        f32x4 accC[2];
        #pragma unroll
        for (int j = 0; j < 2; ++j) {
            f32x4 g;
            #pragma unroll
            for (int r = 0; r < 4; ++r) g[r] = bf2f((ushort)cxr[j][r]);
            accC[j] = g;
        }

        #pragma unroll
        for (int tap = 0; tap < 9; ++tap) {
            const int ky = tap / 3, kx = tap - ky * 3;
            #pragma unroll
            for (int kc = 0; kc < 2; ++kc) {
                short8 a = *(const short8*)(wfCh + (size_t)(((tap * 4 + cf) * 2 + kc) * 512) + lane * 8);
                #pragma unroll
                for (int j = 0; j < 2; ++j) {
                    const int tr = ph2 + ky;
                    const int hc = j * 16 + lr + kx;
                    short8 bf = *(const short8*)(rhbuf + (tr * 34 + hc) * 64 + ((((kc << 2) + lg) ^ ((hc + 7) & 7)) << 3));
                    accC[j] = __builtin_amdgcn_mfma_f32_16x16x32_bf16(a, bf, accC[j], 0, 0, 0);
                }
            }
        }
        const float m = mask[b * TT + (TT - 1 - t)];
        const int y = R + ph2;
        #pragma unroll
        for (int j = 0; j < 2; ++j) {
            const int c = j * 16 + lr;
            const int pi = ph2 * 32 + c;
            const int sw = ((co0 >> 2) ^ (c & 15)) << 2;
            const f32x4 ho = *(const f32x4*)(hode + pi * 64 + sw);
            const f32x4 u  = *(const f32x4*)(ubuf + pi * 64 + sw);
            f32x4 o;
            short4v s;
            #pragma unroll
            for (int r = 0; r < 4; ++r) {
                const float cand = fast_tanh(accC[j][r]);
                o[r] = ho[r] + m * u[r] * (cand - ho[r]);
                s[r] = (short)f2bf(o[r]);
            }
            const int pix = y * 32 + c;
            *(f32x4*)(h_out + (size_t)b * 65536 + (size_t)pix * 64 + co0) = o;
            *(short4v*)(h_outb + ((size_t)b * 1026 + 1 + pix) * 64
                        + (((co0 >> 3) ^ (c & 7)) << 3) + (co0 & 7)) = s;
        }
    }
}

// Head: z = relu(W1 h + b1); z2 = W2 z + b2; out NCHW (mean, |std|)
__global__ __launch_bounds__(256)
void head_mfma(const float* __restrict__ h,
               const ushort* __restrict__ w1f, const float* __restrict__ b1,
               const ushort* __restrict__ w2f, const float* __restrict__ b2,
               float* __restrict__ outp)
{
    __shared__ ushort hlds[64 * 64];
    __shared__ ushort zlds[64 * 64];
    const int blk = blockIdx.x, b = blk >> 4, pixb = (blk & 15) * 64;
    const int tid = threadIdx.x, wv = tid >> 6, lane = tid & 63, lr = lane & 15, lg = lane >> 4;
    const float* hb = h + ((size_t)b * 1024 + pixb) * 64;

    for (int idx = tid; idx < 64 * 8; idx += 256) {
        const int c = idx & 7, px = idx >> 3;
        const float4* p = (const float4*)(hb + (size_t)px * 64 + c * 8);
        *(short8*)(hlds + px * 64 + ((c ^ (px & 7)) << 3)) = pack8(p[0], p[1]);
    }
    __syncthreads();

    f32x4 acc1[4]; acc1[0]=0; acc1[1]=0; acc1[2]=0; acc1[3]=0;
    #pragma unroll
    for (int kc = 0; kc < 2; ++kc) {
        short8 a = *(const short8*)(w1f + (((size_t)wv * 2 + kc) * 64 + lane) * 8);
        #pragma unroll
        for (int p = 0; p < 4; ++p) {
            const int hp = p * 16 + lr;
            short8 bf = *(const short8*)(hlds + hp * 64 + (((kc * 4 + lg) ^ (hp & 7)) << 3));
            acc1[p] = __builtin_amdgcn_mfma_f32_16x16x32_bf16(a, bf, acc1[p], 0, 0, 0);
        }
    }
    {
        const int co0 = wv * 16 + lg * 4;
        const f32x4 b4 = *(const f32x4*)(b1 + co0);
        #pragma unroll
        for (int p = 0; p < 4; ++p) {
            const int px = p * 16 + lr;
            short4v s;
            #pragma unroll
            for (int r = 0; r < 4; ++r)
                s[r] = (short)f2bf(fmaxf(acc1[p][r] + b4[r], 0.0f));
            *(short4v*)(zlds + px * 64 + (((co0 >> 3) ^ (px & 7)) << 3) + (co0 & 7)) = s;
        }
    }
    __syncthreads();

    f32x4 acc2[2][4];
    #pragma unroll
    for (int gi = 0; gi < 2; ++gi)
        #pragma unroll
        for (int p = 0; p < 4; ++p) acc2[gi][p] = 0;
    #pragma unroll
    for (int kc = 0; kc < 2; ++kc) {
        short8 a0 = *(const short8*)(w2f + ((((size_t)wv * 2 + 0) * 2 + kc) * 64 + lane) * 8);
        short8 a1 = *(const short8*)(w2f + ((((size_t)wv * 2 + 1) * 2 + kc) * 64 + lane) * 8);
        #pragma unroll
        for (int p = 0; p < 4; ++p) {
            const int hp = p * 16 + lr;
            short8 bf = *(const short8*)(zlds + hp * 64 + (((kc * 4 + lg) ^ (hp & 7)) << 3));
            acc2[0][p] = __builtin_amdgcn_mfma_f32_16x16x32_bf16(a0, bf, acc2[0][p], 0, 0, 0);
            acc2[1][p] = __builtin_amdgcn_mfma_f32_16x16x32_bf16(a1, bf, acc2[1][p], 0, 0, 0);
        }
    }
    #pragma unroll
    for (int gi = 0; gi < 2; ++gi) {
        const int co0 = wv * 32 + gi * 16 + lg * 4;
        const f32x4 b4 = *(const f32x4*)(b2 + co0);
        #pragma unroll
        for (int p = 0; p < 4; ++p) {
            const int px = pixb + p * 16 + lr;
            #pragma unroll
            for (int r = 0; r < 4; ++r) {
                const int co = co0 + r;
                const float v = acc2[gi][p][r] + b4[r];
                if (co < 64)
                    outp[((size_t)b * 64 + co) * 1024 + px] = v;
                else
                    outp[(size_t)BB * 64 * 1024 + ((size_t)b * 64 + (co - 64)) * 1024 + px] = fabsf(v);
            }
        }
    }
}

extern "C" void kernel_launch(void* const* d_in, const int* in_sizes, int n_in,
                              void* d_out, int out_size, void* d_ws, size_t ws_size,
                              hipStream_t stream)
{
    const float* xall    = (const float*)d_in[0];
    const float* tsteps  = (const float*)d_in[1];
    const float* mask    = (const float*)d_in[2];
    const float* w_gates = (const float*)d_in[3];
    const float* b_gates = (const float*)d_in[4];
    const float* w_can   = (const float*)d_in[5];
    const float* b_can   = (const float*)d_in[6];
    const float* w_ode   = (const float*)d_in[7];
    const float* b_ode   = (const float*)d_in[8];
    const float* w_t1    = (const float*)d_in[9];
    const float* b_t1    = (const float*)d_in[10];
    const float* w_t2    = (const float*)d_in[11];
    const float* b_t2    = (const float*)d_in[12];
    float* out = (float*)d_out;

    float*  h0   = (float*)d_ws;
    float*  h1   = h0 + (size_t)BB * 65536;
    ushort* h0b  = (ushort*)(h1 + (size_t)BB * 65536);
    ushort* h1b  = h0b + (size_t)BB * 1026 * 64;
    ushort* axc  = h1b + (size_t)BB * 1026 * 64;
    ushort* x_cl = axc + (size_t)256 * 1024 * 192;
    ushort* wfX  = x_cl + (size_t)BB * TT * 1026 * 64;
    ushort* wfGh = wfX  + (size_t)216 * 512;
    ushort* wfCh = wfGh + (size_t)144 * 512;
    ushort* wfO  = wfCh + (size_t)72 * 512;
    ushort* wf1  = wfO  + (size_t)72 * 512;
    ushort* wf2  = wf1  + (size_t)8 * 512;

    hipMemsetAsync(h0, 0, (size_t)BB * 65536 * sizeof(float), stream);
    hipMemsetAsync(h0b, 0, (size_t)BB * 1026 * 64 * 2 * sizeof(ushort), stream);

    x_transpose<<<dim3(256, 4), 256, 0, stream>>>(xall, x_cl);
    pack_all<<<dim3(132), 256, 0, stream>>>(w_gates, w_can, w_ode, w_t1, w_t2,
                                            wfX, wfGh, wfCh, wfO, wf1, wf2);
    conv_x192<<<dim3(8, 256), 512, 0, stream>>>(x_cl, wfX, b_gates, b_can, axc);

    hipFuncSetAttribute(reinterpret_cast<const void*>(fused_step),
                        hipFuncAttributeMaxDynamicSharedMemorySize, 77312);

    for (int t = 0; t < TT; ++t) {
        const float*  hin   = (t & 1) ? h1  : h0;
        float*        hout  = (t & 1) ? h0  : h1;
        const ushort* hinb  = (t & 1) ? h1b : h0b;
        ushort*       houtb = (t & 1) ? h0b : h1b;
        fused_step<<<dim3(16, BB), 512, 77312, stream>>>(axc, hin, hinb, hout, houtb,
                                                         wfO, wfGh, wfCh,
                                                         b_ode, tsteps, mask, t);
    }
    head_mfma<<<dim3(256), 256, 0, stream>>>(h0, wf1, b_t1, wf2, b_t2, out);
}

// Round 13
// 417.317 us; speedup vs baseline: 2.2697x; 1.0797x over previous
//
#include <hip/hip_runtime.h>
#include <hip/hip_bf16.h>

#define BB 16
#define TT 16

typedef short short8  __attribute__((ext_vector_type(8)));
typedef short short4v __attribute__((ext_vector_type(4)));
typedef float f32x4   __attribute__((ext_vector_type(4)));

__device__ __forceinline__ ushort f2bf(float f) {
    uint u = __float_as_uint(f);
    u += 0x7FFFu + ((u >> 16) & 1u);      // RTNE
    return (ushort)(u >> 16);
}
__device__ __forceinline__ float bf2f(ushort h) { return __uint_as_float(((uint)h) << 16); }
__device__ __forceinline__ float fast_sigmoid(float x) { return 1.0f / (1.0f + __expf(-x)); }
__device__ __forceinline__ float fast_tanh(float x) {
    float e = __expf(2.0f * x);
    return 1.0f - 2.0f / (e + 1.0f);
}

// One kernel packs ALL weight tensors into bf16 MFMA A-fragments.
__global__ __launch_bounds__(256)
void pack_all(const float* __restrict__ wg, const float* __restrict__ wc,
              const float* __restrict__ wo, const float* __restrict__ w1,
              const float* __restrict__ w2,
              ushort* __restrict__ wfX, ushort* __restrict__ wfGh,
              ushort* __restrict__ wfCh, ushort* __restrict__ wfO,
              ushort* __restrict__ wf1, ushort* __restrict__ wf2)
{
    const int gi = blockIdx.x * 256 + threadIdx.x;
    const int fi = gi >> 6, lane = gi & 63;
    if (fi >= 528) return;
    const float* src; ushort* dst;
    int CINfull, ci_base, cb_base, CBn, CBT, NT, lf;
    if (fi < 144)      { lf=fi;     src=wg; dst=wfX;  CINfull=128; ci_base=0;  cb_base=0; CBn=8; CBT=12; NT=9; }
    else if (fi < 216) { lf=fi-144; src=wc; dst=wfX;  CINfull=128; ci_base=0;  cb_base=8; CBn=4; CBT=12; NT=9; }
    else if (fi < 360) { lf=fi-216; src=wg; dst=wfGh; CINfull=128; ci_base=64; cb_base=0; CBn=8; CBT=8;  NT=9; }
    else if (fi < 432) { lf=fi-360; src=wc; dst=wfCh; CINfull=128; ci_base=64; cb_base=0; CBn=4; CBT=4;  NT=9; }
    else if (fi < 504) { lf=fi-432; src=wo; dst=wfO;  CINfull=64;  ci_base=0;  cb_base=0; CBn=4; CBT=4;  NT=9; }
    else if (fi < 512) { lf=fi-504; src=w1; dst=wf1;  CINfull=64;  ci_base=0;  cb_base=0; CBn=4; CBT=4;  NT=1; }
    else               { lf=fi-512; src=w2; dst=wf2;  CINfull=64;  ci_base=0;  cb_base=0; CBn=8; CBT=8;  NT=1; }
    const int KCp = 2;
    const int kc = lf % KCp;
    const int cb = (lf / KCp) % CBn;
    const int tap = lf / (KCp * CBn);
    const int co  = cb * 16 + (lane & 15);
    const int ci0 = ci_base + kc * 32 + (lane >> 4) * 8;
    short8 v;
    #pragma unroll
    for (int e = 0; e < 8; ++e)
        v[e] = (short)f2bf(src[((size_t)co * CINfull + ci0 + e) * NT + tap]);
    const size_t fo = ((size_t)(tap * CBT + cb_base + cb)) * KCp + kc;
    *(short8*)(dst + (fo * 64 + lane) * 8) = v;
}

// Merged x-transpose + x-conv: reads x fp32 NCHW, writes Axc[bt][pix][192].
// fraw stride 203 floats (8*203 % 32 = 24 -> <=2-way LDS banks, free).
// LDS: xb bf16-swz [0,13056) ushorts ; fraw fp32 @ushort 13056 (64ch x 203f, 51968B)
//   overlay after conv: outb ushorts @13056 (128px x 200).  Total 78080 B.
__global__ __launch_bounds__(512)
void conv_x(const float* __restrict__ xall,
            const ushort* __restrict__ wfX,
            const float* __restrict__ b_gates,
            const float* __restrict__ b_can,
            ushort* __restrict__ axc)
{
    extern __shared__ ushort smem[];
    ushort* xb   = smem;
    float*  fraw = (float*)(smem + 13056);
    ushort* outb = smem + 13056;

    const int rt = blockIdx.x, bt = blockIdx.y;
    const int R  = rt * 4;
    const int tid = threadIdx.x;
    const int w = tid >> 6, lane = tid & 63, lr = lane & 15, lg = lane >> 4;
    const float* xs = xall + (size_t)bt * 65536;

    // stage fp32 rows R-1..R+4 (coalesced float4), stride-203 LDS
    for (int i = tid; i < 3072; i += 512) {
        const int ch = i / 48, rem = i - ch * 48;
        const int tr = rem >> 3, q = rem & 7;
        const int y = R - 1 + tr;
        if ((unsigned)y < 32u)
            *(float4*)(fraw + ch * 203 + tr * 32 + q * 4) =
                *(const float4*)(xs + (size_t)ch * 1024 + y * 32 + q * 4);
    }
    __syncthreads();

    // convert -> bf16 swizzled halo tile
    for (int i = tid; i < 1632; i += 512) {
        const int tr = i / 272, rem = i - tr * 272;
        const int hc = rem >> 3, c8 = rem & 7;
        const int y = R - 1 + tr, x = hc - 1;
        short8 v = (short8)0;
        if ((unsigned)y < 32u && (unsigned)x < 32u) {
            #pragma unroll
            for (int e = 0; e < 8; ++e)
                v[e] = (short)f2bf(fraw[(c8 * 8 + e) * 203 + tr * 32 + x]);
        }
        *(short8*)(xb + (tr * 34 + hc) * 64 + ((c8 ^ ((hc + 7) & 7)) << 3)) = v;
    }
    __syncthreads();

    const int cb0 = (w & 3) * 3;
    const int pf0 = (w >> 2) * 4;

    f32x4 acc[3][4];
    #pragma unroll
    for (int i = 0; i < 3; ++i)
        #pragma unroll
        for (int j = 0; j < 4; ++j) acc[i][j] = 0;

    #pragma unroll
    for (int tap = 0; tap < 9; ++tap) {
        const int ky = tap / 3, kx = tap - ky * 3;
        #pragma unroll
        for (int kc = 0; kc < 2; ++kc) {
            short8 a[3];
            #pragma unroll
            for (int i = 0; i < 3; ++i)
                a[i] = *(const short8*)(wfX + (size_t)(((tap * 12 + cb0 + i) * 2 + kc) * 512) + lane * 8);
            #pragma unroll
            for (int j = 0; j < 4; ++j) {
                const int px = (pf0 + j) * 16 + lr;
                const int tr = (px >> 5) + ky, hc = (px & 31) + kx;
                short8 bf = *(const short8*)(xb + (tr * 34 + hc) * 64 + (((kc * 4 + lg) ^ ((hc + 7) & 7)) << 3));
                #pragma unroll
                for (int i = 0; i < 3; ++i)
                    acc[i][j] = __builtin_amdgcn_mfma_f32_16x16x32_bf16(a[i], bf, acc[i][j], 0, 0, 0);
            }
        }
    }
    __syncthreads();     // xb/fraw reads complete; overlay outb

    #pragma unroll
    for (int i = 0; i < 3; ++i) {
        const int co0 = (cb0 + i) * 16 + lg * 4;
        const float* bsrc = (co0 < 128) ? (b_gates + co0) : (b_can + co0 - 128);
        const f32x4 b4 = *(const f32x4*)bsrc;
        #pragma unroll
        for (int j = 0; j < 4; ++j) {
            const int px = (pf0 + j) * 16 + lr;
            short4v s;
            #pragma unroll
            for (int r = 0; r < 4; ++r)
                s[r] = (short)f2bf(acc[i][j][r] + b4[r]);
            *(short4v*)(outb + px * 200 + co0) = s;
        }
    }
    __syncthreads();

    ushort* dst = axc + (((size_t)bt * 1024) + R * 32) * 192;
    for (int i = tid; i < 3072; i += 512) {
        const int px = i / 24, c = i - px * 24;
        *(short8*)(dst + (size_t)px * 192 + c * 8) = *(const short8*)(outb + px * 200 + c * 8);
    }
}

// ---- fused ConvGRU-ODE step (R7-proven structure): 2-row tiles, 256 blocks ----
// Phase-A epilogue: fp32 h only for owned rows; halo rows use bf16 h from hbuf.
__global__ __launch_bounds__(512, 1)
void fused_step(const ushort* __restrict__ axc,
                const float* __restrict__ h_in,
                const ushort* __restrict__ h_inb,
                float* __restrict__ h_out,
                ushort* __restrict__ h_outb,
                const ushort* __restrict__ wfO,
                const ushort* __restrict__ wfGh,
                const ushort* __restrict__ wfCh,
                const float* __restrict__ b_ode,
                const float* __restrict__ tsteps,
                const float* __restrict__ mask,
                int t)
{
    extern __shared__ ushort smem[];
    float*  smemf = (float*)smem;
    ushort* hbuf  = smem;
    ushort* obuf  = smem + 17408;
    ushort* rhbuf = smem;
    float*  ubuf  = smemf + 4352;
    float*  hode  = smemf + 15232;

    const int rt = blockIdx.x, b = blockIdx.y;
    const int R  = rt * 2;
    const int tid = threadIdx.x;
    const int w = tid >> 6, lane = tid & 63, lr = lane & 15, lg = lane >> 4;
    const int bti = b * TT + (TT - 1 - t);

    const ushort* hbb = h_inb + (size_t)b * 1026 * 64;
    const float*  hb  = h_in  + (size_t)b * 65536;
    const ushort* axb = axc + (size_t)bti * 1024 * 192;

    // ---- hoisted Gx/Cx acc-init loads ----
    short4v gxr[2][4], cxr[2];
    {
        const int cq = w & 3, ph = w >> 2;
        #pragma unroll
        for (int i = 0; i < 2; ++i) {
            const int cog0 = (2 * cq + i) * 16 + lg * 4;
            #pragma unroll
            for (int j = 0; j < 4; ++j) {
                const int f = 4 * ph + j;
                const int y = R - 1 + (f >> 1);
                const int c = (f & 1) * 16 + lr;
                short4v g = (short4v)0;
                if ((unsigned)y < 32u)
                    g = *(const short4v*)(axb + ((size_t)(y * 32 + c)) * 192 + cog0);
                gxr[i][j] = g;
            }
        }
        const int cf = w & 3, ph2 = w >> 2;
        const int co0 = cf * 16 + lg * 4;
        #pragma unroll
        for (int j = 0; j < 2; ++j) {
            const int c = j * 16 + lr;
            const int pix = (R + (ph2 & 1)) * 32 + c;
            cxr[j] = *(const short4v*)(axb + (size_t)pix * 192 + 128 + co0);
        }
    }

    // ---- stage: hbuf rows R-3..R+4 ; obuf halo cols + OOB rows zero ----
    for (int i = tid; i < 2176; i += 512) {
        const int tr = i / 272, rem = i - tr * 272;
        const int hc = rem >> 3;
        const int y  = R - 3 + tr;
        short8 v = (short8)0;
        if ((unsigned)y < 32u && hc != 0 && hc != 33)
            v = *(const short8*)(hbb + ((size_t)(y * 32 + hc)) * 64 + (rem & 7) * 8);
        *(short8*)(hbuf + (size_t)i * 8) = v;
    }
    for (int i = tid; i < 1632; i += 512) {
        const int tr = i / 272, rem = i - tr * 272;
        const int hc = rem >> 3;
        const int y  = R - 2 + tr;
        if (hc == 0 || hc == 33 || (unsigned)y >= 32u)
            *(short8*)(obuf + (size_t)i * 8) = (short8)0;
    }
    __syncthreads();

    // ---- phase A: h_ode rows R-2..R+3 (K=64 over hbuf) ----
    {
        const int cb0 = (w & 1) * 2;
        const int pxg = w >> 1;
        f32x4 accA[2][3];
        #pragma unroll
        for (int i = 0; i < 2; ++i)
            #pragma unroll
            for (int j = 0; j < 3; ++j) accA[i][j] = 0;

        #pragma unroll
        for (int tap = 0; tap < 9; ++tap) {
            const int ky = tap / 3, kx = tap - ky * 3;
            #pragma unroll
            for (int kc = 0; kc < 2; ++kc) {
                short8 a0 = *(const short8*)(wfO + (size_t)(((tap * 4 + cb0 + 0) * 2 + kc) * 512) + lane * 8);
                short8 a1 = *(const short8*)(wfO + (size_t)(((tap * 4 + cb0 + 1) * 2 + kc) * 512) + lane * 8);
                #pragma unroll
                for (int j = 0; j < 3; ++j) {
                    const int p  = (3 * pxg + j) * 16 + lr;
                    const int tr = (p >> 5) + ky, hc = (p & 31) + kx;
                    short8 bf = *(const short8*)(hbuf + (tr * 34 + hc) * 64 + ((((kc << 2) + lg) ^ ((hc + 7) & 7)) << 3));
                    accA[0][j] = __builtin_amdgcn_mfma_f32_16x16x32_bf16(a0, bf, accA[0][j], 0, 0, 0);
                    accA[1][j] = __builtin_amdgcn_mfma_f32_16x16x32_bf16(a1, bf, accA[1][j], 0, 0, 0);
                }
            }
        }
        const float dt = (t == 0) ? -0.01f : (tsteps[TT - 1 - t] - tsteps[TT - t]);
        #pragma unroll
        for (int i = 0; i < 2; ++i) {
            #pragma unroll
            for (int j = 0; j < 3; ++j) {
                const int co0 = (cb0 + i) * 16 + lg * 4;
                const int p = (3 * pxg + j) * 16 + lr;
                const int orow = p >> 5, c = p & 31;
                const int y = R - 2 + orow;
                if ((unsigned)y < 32u) {
                    const int key = (((co0 >> 3) ^ (c & 7)) << 3) + (co0 & 7);
                    f32x4 h4;
                    if ((unsigned)(y - R) < 2u) {       // owned rows: exact fp32 chain
                        h4 = *(const f32x4*)(hb + ((size_t)(y * 32 + c)) * 64 + co0);
                    } else {                             // halo rows: bf16 h from hbuf
                        short4v hv = *(const short4v*)(hbuf + ((orow + 1) * 34 + c + 1) * 64 + key);
                        #pragma unroll
                        for (int r = 0; r < 4; ++r) h4[r] = bf2f((ushort)hv[r]);
                    }
                    const f32x4 b4 = *(const f32x4*)(b_ode + co0);
                    f32x4 ho;
                    #pragma unroll
                    for (int r = 0; r < 4; ++r)
                        ho[r] = h4[r] + fast_tanh(accA[i][j][r] + b4[r]) * dt;
                    short4v s;
                    #pragma unroll
                    for (int r = 0; r < 4; ++r) s[r] = (short)f2bf(ho[r]);
                    *(short4v*)(obuf + (orow * 34 + c + 1) * 64 + key) = s;
                    if ((unsigned)(y - R) < 2u)
                        *(f32x4*)(hode + ((y - R) * 32 + c) * 64 + (((co0 >> 2) ^ (c & 15)) << 2)) = ho;
                }
            }
        }
    }
    __syncthreads();

    // rhbuf: zero halo cols + OOB rows (overlays dead hbuf)
    for (int i = tid; i < 1088; i += 512) {
        const int tr = i / 272, rem = i - tr * 272;
        const int hc = rem >> 3;
        const int y  = R - 1 + tr;
        if (hc == 0 || hc == 33 || (unsigned)y >= 32u)
            *(short8*)(rhbuf + (size_t)i * 8) = (short8)0;
    }

    // ---- phase B: gates rows R-1..R+2 (K=64 over obuf, acc init from Gx) ----
    {
        const int cq = w & 3, ph = w >> 2;
        f32x4 accB[2][4];
        #pragma unroll
        for (int i = 0; i < 2; ++i)
            #pragma unroll
            for (int j = 0; j < 4; ++j) {
                f32x4 g;
                #pragma unroll
                for (int r = 0; r < 4; ++r) g[r] = bf2f((ushort)gxr[i][j][r]);
                accB[i][j] = g;
            }

        #pragma unroll
        for (int tap = 0; tap < 9; ++tap) {
            const int ky = tap / 3, kx = tap - ky * 3;
            #pragma unroll
            for (int kc = 0; kc < 2; ++kc) {
                short8 a0 = *(const short8*)(wfGh + (size_t)(((tap * 8 + 2 * cq + 0) * 2 + kc) * 512) + lane * 8);
                short8 a1 = *(const short8*)(wfGh + (size_t)(((tap * 8 + 2 * cq + 1) * 2 + kc) * 512) + lane * 8);
                #pragma unroll
                for (int j = 0; j < 4; ++j) {
                    const int f  = 4 * ph + j;
                    const int tr = (f >> 1) + ky;
                    const int hc = (f & 1) * 16 + lr + kx;
                    short8 bf = *(const short8*)(obuf + (tr * 34 + hc) * 64 + ((((kc << 2) + lg) ^ ((hc + 7) & 7)) << 3));
                    accB[0][j] = __builtin_amdgcn_mfma_f32_16x16x32_bf16(a0, bf, accB[0][j], 0, 0, 0);
                    accB[1][j] = __builtin_amdgcn_mfma_f32_16x16x32_bf16(a1, bf, accB[1][j], 0, 0, 0);
                }
            }
        }
        #pragma unroll
        for (int i = 0; i < 2; ++i) {
            const int cog = (2 * cq + i) * 16 + lg * 4;
            #pragma unroll
            for (int j = 0; j < 4; ++j) {
                const int f = 4 * ph + j;
                const int y = R - 1 + (f >> 1);
                const int c = (f & 1) * 16 + lr;
                if (cq < 2) {
                    if ((unsigned)y < 32u) {
                        const int tro = (f >> 1) + 1;
                        const int key = (((cog >> 3) ^ (c & 7)) << 3) + (cog & 7);
                        short4v ho4 = *(const short4v*)(obuf + (tro * 34 + c + 1) * 64 + key);
                        short4v s;
                        #pragma unroll
                        for (int r = 0; r < 4; ++r)
                            s[r] = (short)f2bf(fast_sigmoid(accB[i][j][r]) * bf2f((ushort)ho4[r]));
                        *(short4v*)(rhbuf + ((f >> 1) * 34 + c + 1) * 64 + key) = s;
                    }
                } else if ((unsigned)(y - R) < 2u) {
                    const int cu = cog - 64;
                    f32x4 u;
                    #pragma unroll
                    for (int r = 0; r < 4; ++r)
                        u[r] = fast_sigmoid(accB[i][j][r]);
                    *(f32x4*)(ubuf + ((y - R) * 32 + c) * 64 + (((cu >> 2) ^ (c & 15)) << 2)) = u;
                }
            }
        }
    }
    __syncthreads();

    // ---- phase C: cand rows R..R+1 (K=64 over rhbuf, acc init from Cx) ; GRU update ----
    {
        const int cf = w & 3, ph2 = w >> 2;
        const int co0 = cf * 16 + lg * 4;
        f32x4 accC[2];
        #pragma unroll
        for (int j = 0; j < 2; ++j) {
            f32x4 g;
            #pragma unroll
            for (int r = 0; r < 4; ++r) g[r] = bf2f((ushort)cxr[j][r]);
            accC[j] = g;
        }

        #pragma unroll
        for (int tap = 0; tap < 9; ++tap) {
            const int ky = tap / 3, kx = tap - ky * 3;
            #pragma unroll
            for (int kc = 0; kc < 2; ++kc) {
                short8 a = *(const short8*)(wfCh + (size_t)(((tap * 4 + cf) * 2 + kc) * 512) + lane * 8);
                #pragma unroll
                for (int j = 0; j < 2; ++j) {
                    const int tr = ph2 + ky;
                    const int hc = j * 16 + lr + kx;
                    short8 bf = *(const short8*)(rhbuf + (tr * 34 + hc) * 64 + ((((kc << 2) + lg) ^ ((hc + 7) & 7)) << 3));
                    accC[j] = __builtin_amdgcn_mfma_f32_16x16x32_bf16(a, bf, accC[j], 0, 0, 0);
                }
            }
        }
        const float m = mask[b * TT + (TT - 1 - t)];
        const int y = R + ph2;
        #pragma unroll
        for (int j = 0; j < 2; ++j) {
            const int c = j * 16 + lr;
            const int pi = ph2 * 32 + c;
            const int sw = ((co0 >> 2) ^ (c & 15)) << 2;
            const f32x4 ho = *(const f32x4*)(hode + pi * 64 + sw);
            const f32x4 u  = *(const f32x4*)(ubuf + pi * 64 + sw);
            f32x4 o;
            short4v s;
            #pragma unroll
            for (int r = 0; r < 4; ++r) {
                const float cand = fast_tanh(accC[j][r]);
                o[r] = ho[r] + m * u[r] * (cand - ho[r]);
                s[r] = (short)f2bf(o[r]);
            }
            const int pix = y * 32 + c;
            *(f32x4*)(h_out + (size_t)b * 65536 + (size_t)pix * 64 + co0) = o;
            *(short4v*)(h_outb + ((size_t)b * 1026 + 1 + pix) * 64
                        + (((co0 >> 3) ^ (c & 7)) << 3) + (co0 & 7)) = s;
        }
    }
}

// Head: z = relu(W1 h + b1); z2 = W2 z + b2; out NCHW (mean, |std|)
__global__ __launch_bounds__(256)
void head_mfma(const float* __restrict__ h,
               const ushort* __restrict__ w1f, const float* __restrict__ b1,
               const ushort* __restrict__ w2f, const float* __restrict__ b2,
               float* __restrict__ outp)
{
    __shared__ ushort hlds[64 * 64];
    __shared__ ushort zlds[64 * 64];
    const int blk = blockIdx.x, b = blk >> 4, pixb = (blk & 15) * 64;
    const int tid = threadIdx.x, wv = tid >> 6, lane = tid & 63, lr = lane & 15, lg = lane >> 4;
    const float* hb = h + ((size_t)b * 1024 + pixb) * 64;

    for (int idx = tid; idx < 64 * 8; idx += 256) {
        const int c = idx & 7, px = idx >> 3;
        const float4* p = (const float4*)(hb + (size_t)px * 64 + c * 8);
        short8 v;
        #pragma unroll
        for (int e = 0; e < 4; ++e) { v[e] = (short)f2bf(((const float*)p)[e]); v[e+4] = (short)f2bf(((const float*)p)[e+4]); }
        *(short8*)(hlds + px * 64 + ((c ^ (px & 7)) << 3)) = v;
    }
    __syncthreads();

    f32x4 acc1[4]; acc1[0]=0; acc1[1]=0; acc1[2]=0; acc1[3]=0;
    #pragma unroll
    for (int kc = 0; kc < 2; ++kc) {
        short8 a = *(const short8*)(w1f + (((size_t)wv * 2 + kc) * 64 + lane) * 8);
        #pragma unroll
        for (int p = 0; p < 4; ++p) {
            const int hp = p * 16 + lr;
            short8 bf = *(const short8*)(hlds + hp * 64 + (((kc * 4 + lg) ^ (hp & 7)) << 3));
            acc1[p] = __builtin_amdgcn_mfma_f32_16x16x32_bf16(a, bf, acc1[p], 0, 0, 0);
        }
    }
    {
        const int co0 = wv * 16 + lg * 4;
        const f32x4 b4 = *(const f32x4*)(b1 + co0);
        #pragma unroll
        for (int p = 0; p < 4; ++p) {
            const int px = p * 16 + lr;
            short4v s;
            #pragma unroll
            for (int r = 0; r < 4; ++r)
                s[r] = (short)f2bf(fmaxf(acc1[p][r] + b4[r], 0.0f));
            *(short4v*)(zlds + px * 64 + (((co0 >> 3) ^ (px & 7)) << 3) + (co0 & 7)) = s;
        }
    }
    __syncthreads();

    f32x4 acc2[2][4];
    #pragma unroll
    for (int gi = 0; gi < 2; ++gi)
        #pragma unroll
        for (int p = 0; p < 4; ++p) acc2[gi][p] = 0;
    #pragma unroll
    for (int kc = 0; kc < 2; ++kc) {
        short8 a0 = *(const short8*)(w2f + ((((size_t)wv * 2 + 0) * 2 + kc) * 64 + lane) * 8);
        short8 a1 = *(const short8*)(w2f + ((((size_t)wv * 2 + 1) * 2 + kc) * 64 + lane) * 8);
        #pragma unroll
        for (int p = 0; p < 4; ++p) {
            const int hp = p * 16 + lr;
            short8 bf = *(const short8*)(zlds + hp * 64 + (((kc * 4 + lg) ^ (hp & 7)) << 3));
            acc2[0][p] = __builtin_amdgcn_mfma_f32_16x16x32_bf16(a0, bf, acc2[0][p], 0, 0, 0);
            acc2[1][p] = __builtin_amdgcn_mfma_f32_16x16x32_bf16(a1, bf, acc2[1][p], 0, 0, 0);
        }
    }
    #pragma unroll
    for (int gi = 0; gi < 2; ++gi) {
        const int co0 = wv * 32 + gi * 16 + lg * 4;
        const f32x4 b4 = *(const f32x4*)(b2 + co0);
        #pragma unroll
        for (int p = 0; p < 4; ++p) {
            const int px = pixb + p * 16 + lr;
            #pragma unroll
            for (int r = 0; r < 4; ++r) {
                const int co = co0 + r;
                const float v = acc2[gi][p][r] + b4[r];
                if (co < 64)
                    outp[((size_t)b * 64 + co) * 1024 + px] = v;
                else
                    outp[(size_t)BB * 64 * 1024 + ((size_t)b * 64 + (co - 64)) * 1024 + px] = fabsf(v);
            }
        }
    }
}

extern "C" void kernel_launch(void* const* d_in, const int* in_sizes, int n_in,
                              void* d_out, int out_size, void* d_ws, size_t ws_size,
                              hipStream_t stream)
{
    const float* xall    = (const float*)d_in[0];
    const float* tsteps  = (const float*)d_in[1];
    const float* mask    = (const float*)d_in[2];
    const float* w_gates = (const float*)d_in[3];
    const float* b_gates = (const float*)d_in[4];
    const float* w_can   = (const float*)d_in[5];
    const float* b_can   = (const float*)d_in[6];
    const float* w_ode   = (const float*)d_in[7];
    const float* b_ode   = (const float*)d_in[8];
    const float* w_t1    = (const float*)d_in[9];
    const float* b_t1    = (const float*)d_in[10];
    const float* w_t2    = (const float*)d_in[11];
    const float* b_t2    = (const float*)d_in[12];
    float* out = (float*)d_out;

    float*  h0   = (float*)d_ws;
    float*  h1   = h0 + (size_t)BB * 65536;
    ushort* h0b  = (ushort*)(h1 + (size_t)BB * 65536);
    ushort* h1b  = h0b + (size_t)BB * 1026 * 64;
    ushort* axc  = h1b + (size_t)BB * 1026 * 64;
    ushort* wfX  = axc + (size_t)256 * 1024 * 192;
    ushort* wfGh = wfX  + (size_t)216 * 512;
    ushort* wfCh = wfGh + (size_t)144 * 512;
    ushort* wfO  = wfCh + (size_t)72 * 512;
    ushort* wf1  = wfO  + (size_t)72 * 512;
    ushort* wf2  = wf1  + (size_t)8 * 512;

    hipMemsetAsync(h0, 0, (size_t)BB * 65536 * sizeof(float), stream);
    hipMemsetAsync(h0b, 0, (size_t)BB * 1026 * 64 * 2 * sizeof(ushort), stream);

    pack_all<<<dim3(132), 256, 0, stream>>>(w_gates, w_can, w_ode, w_t1, w_t2,
                                            wfX, wfGh, wfCh, wfO, wf1, wf2);

    hipFuncSetAttribute(reinterpret_cast<const void*>(conv_x),
                        hipFuncAttributeMaxDynamicSharedMemorySize, 78080);
    conv_x<<<dim3(8, 256), 512, 78080, stream>>>(xall, wfX, b_gates, b_can, axc);

    hipFuncSetAttribute(reinterpret_cast<const void*>(fused_step),
                        hipFuncAttributeMaxDynamicSharedMemorySize, 77312);

    for (int t = 0; t < TT; ++t) {
        const float*  hin   = (t & 1) ? h1  : h0;
        float*        hout  = (t & 1) ? h0  : h1;
        const ushort* hinb  = (t & 1) ? h1b : h0b;
        ushort*       houtb = (t & 1) ? h0b : h1b;
        fused_step<<<dim3(16, BB), 512, 77312, stream>>>(axc, hin, hinb, hout, houtb,
                                                         wfO, wfGh, wfCh,
                                                         b_ode, tsteps, mask, t);
    }
    head_mfma<<<dim3(256), 256, 0, stream>>>(h0, wf1, b_t1, wf2, b_t2, out);
}

// Round 14
// 396.623 us; speedup vs baseline: 2.3881x; 1.0522x over previous
//
#include <hip/hip_runtime.h>
#include <hip/hip_bf16.h>

#define BB 16
#define TT 16

typedef short short8  __attribute__((ext_vector_type(8)));
typedef short short4v __attribute__((ext_vector_type(4)));
typedef float f32x4   __attribute__((ext_vector_type(4)));

__device__ __forceinline__ ushort f2bf(float f) {
    uint u = __float_as_uint(f);
    u += 0x7FFFu + ((u >> 16) & 1u);      // RTNE
    return (ushort)(u >> 16);
}
__device__ __forceinline__ float bf2f(ushort h) { return __uint_as_float(((uint)h) << 16); }
__device__ __forceinline__ float fast_sigmoid(float x) { return 1.0f / (1.0f + __expf(-x)); }
__device__ __forceinline__ float fast_tanh(float x) {
    float e = __expf(2.0f * x);
    return 1.0f - 2.0f / (e + 1.0f);
}

// One kernel packs ALL weight tensors into bf16 MFMA A-fragments.
__global__ __launch_bounds__(256)
void pack_all(const float* __restrict__ wg, const float* __restrict__ wc,
              const float* __restrict__ wo, const float* __restrict__ w1,
              const float* __restrict__ w2,
              ushort* __restrict__ wfX, ushort* __restrict__ wfGh,
              ushort* __restrict__ wfCh, ushort* __restrict__ wfO,
              ushort* __restrict__ wf1, ushort* __restrict__ wf2)
{
    const int gi = blockIdx.x * 256 + threadIdx.x;
    const int fi = gi >> 6, lane = gi & 63;
    if (fi >= 528) return;
    const float* src; ushort* dst;
    int CINfull, ci_base, cb_base, CBn, CBT, NT, lf;
    if (fi < 144)      { lf=fi;     src=wg; dst=wfX;  CINfull=128; ci_base=0;  cb_base=0; CBn=8; CBT=12; NT=9; }
    else if (fi < 216) { lf=fi-144; src=wc; dst=wfX;  CINfull=128; ci_base=0;  cb_base=8; CBn=4; CBT=12; NT=9; }
    else if (fi < 360) { lf=fi-216; src=wg; dst=wfGh; CINfull=128; ci_base=64; cb_base=0; CBn=8; CBT=8;  NT=9; }
    else if (fi < 432) { lf=fi-360; src=wc; dst=wfCh; CINfull=128; ci_base=64; cb_base=0; CBn=4; CBT=4;  NT=9; }
    else if (fi < 504) { lf=fi-432; src=wo; dst=wfO;  CINfull=64;  ci_base=0;  cb_base=0; CBn=4; CBT=4;  NT=9; }
    else if (fi < 512) { lf=fi-504; src=w1; dst=wf1;  CINfull=64;  ci_base=0;  cb_base=0; CBn=4; CBT=4;  NT=1; }
    else               { lf=fi-512; src=w2; dst=wf2;  CINfull=64;  ci_base=0;  cb_base=0; CBn=8; CBT=8;  NT=1; }
    const int KCp = 2;
    const int kc = lf % KCp;
    const int cb = (lf / KCp) % CBn;
    const int tap = lf / (KCp * CBn);
    const int co  = cb * 16 + (lane & 15);
    const int ci0 = ci_base + kc * 32 + (lane >> 4) * 8;
    short8 v;
    #pragma unroll
    for (int e = 0; e < 8; ++e)
        v[e] = (short)f2bf(src[((size_t)co * CINfull + ci0 + e) * NT + tap]);
    const size_t fo = ((size_t)(tap * CBT + cb_base + cb)) * KCp + kc;
    *(short8*)(dst + (fo * 64 + lane) * 8) = v;
}

// Merged x-transpose + x-conv: reads x fp32 NCHW, writes Axc[bt][pix][192].
// fraw: ch stride 199 floats (199%32=7), row stride 33 (33%32=1) -> near-even banks.
// LDS: xb bf16-swz [0,13056) ushorts ; fraw fp32 @ushort 13056 (64ch x 199f = 50944B)
//   overlay after conv: outb ushorts @13056 (128px x 200).  Total 77056 B.
__global__ __launch_bounds__(512)
void conv_x(const float* __restrict__ xall,
            const ushort* __restrict__ wfX,
            const float* __restrict__ b_gates,
            const float* __restrict__ b_can,
            ushort* __restrict__ axc)
{
    extern __shared__ ushort smem[];
    ushort* xb   = smem;
    float*  fraw = (float*)(smem + 13056);
    ushort* outb = smem + 13056;

    const int rt = blockIdx.x, bt = blockIdx.y;
    const int R  = rt * 4;
    const int tid = threadIdx.x;
    const int w = tid >> 6, lane = tid & 63, lr = lane & 15, lg = lane >> 4;
    const float* xs = xall + (size_t)bt * 65536;

    // stage fp32 rows R-1..R+4 (coalesced float4)
    for (int i = tid; i < 3072; i += 512) {
        const int ch = i / 48, rem = i - ch * 48;
        const int tr = rem >> 3, q = rem & 7;
        const int y = R - 1 + tr;
        if ((unsigned)y < 32u)
            *(float4*)(fraw + ch * 199 + tr * 33 + q * 4) =
                *(const float4*)(xs + (size_t)ch * 1024 + y * 32 + q * 4);
    }
    __syncthreads();

    // convert -> bf16 swizzled halo tile
    for (int i = tid; i < 1632; i += 512) {
        const int tr = i / 272, rem = i - tr * 272;
        const int hc = rem >> 3, c8 = rem & 7;
        const int y = R - 1 + tr, x = hc - 1;
        short8 v = (short8)0;
        if ((unsigned)y < 32u && (unsigned)x < 32u) {
            #pragma unroll
            for (int e = 0; e < 8; ++e)
                v[e] = (short)f2bf(fraw[(c8 * 8 + e) * 199 + tr * 33 + x]);
        }
        *(short8*)(xb + (tr * 34 + hc) * 64 + ((c8 ^ ((hc + 7) & 7)) << 3)) = v;
    }
    __syncthreads();

    const int cb0 = (w & 3) * 3;
    const int pf0 = (w >> 2) * 4;

    f32x4 acc[3][4];
    #pragma unroll
    for (int i = 0; i < 3; ++i)
        #pragma unroll
        for (int j = 0; j < 4; ++j) acc[i][j] = 0;

    #pragma unroll
    for (int tap = 0; tap < 9; ++tap) {
        const int ky = tap / 3, kx = tap - ky * 3;
        #pragma unroll
        for (int kc = 0; kc < 2; ++kc) {
            short8 a[3];
            #pragma unroll
            for (int i = 0; i < 3; ++i)
                a[i] = *(const short8*)(wfX + (size_t)(((tap * 12 + cb0 + i) * 2 + kc) * 512) + lane * 8);
            #pragma unroll
            for (int j = 0; j < 4; ++j) {
                const int px = (pf0 + j) * 16 + lr;
                const int tr = (px >> 5) + ky, hc = (px & 31) + kx;
                short8 bf = *(const short8*)(xb + (tr * 34 + hc) * 64 + (((kc * 4 + lg) ^ ((hc + 7) & 7)) << 3));
                #pragma unroll
                for (int i = 0; i < 3; ++i)
                    acc[i][j] = __builtin_amdgcn_mfma_f32_16x16x32_bf16(a[i], bf, acc[i][j], 0, 0, 0);
            }
        }
    }
    __syncthreads();     // xb/fraw reads complete; overlay outb

    #pragma unroll
    for (int i = 0; i < 3; ++i) {
        const int co0 = (cb0 + i) * 16 + lg * 4;
        const float* bsrc = (co0 < 128) ? (b_gates + co0) : (b_can + co0 - 128);
        const f32x4 b4 = *(const f32x4*)bsrc;
        #pragma unroll
        for (int j = 0; j < 4; ++j) {
            const int px = (pf0 + j) * 16 + lr;
            short4v s;
            #pragma unroll
            for (int r = 0; r < 4; ++r)
                s[r] = (short)f2bf(acc[i][j][r] + b4[r]);
            *(short4v*)(outb + px * 200 + co0) = s;
        }
    }
    __syncthreads();

    ushort* dst = axc + (((size_t)bt * 1024) + R * 32) * 192;
    for (int i = tid; i < 3072; i += 512) {
        const int px = i / 24, c = i - px * 24;
        *(short8*)(dst + (size_t)px * 192 + c * 8) = *(const short8*)(outb + px * 200 + c * 8);
    }
}

// ---- fused ConvGRU-ODE step (R7-proven structure): 2-row tiles, 256 blocks ----
// 1D grid with XCD swizzle: l%8 = XCD (round-robin); rt pairs (2k,2k+1) co-XCD.
// t==0: h treated as exact zero (no memset, no loads).
__global__ __launch_bounds__(512, 1)
void fused_step(const ushort* __restrict__ axc,
                const float* __restrict__ h_in,
                const ushort* __restrict__ h_inb,
                float* __restrict__ h_out,
                ushort* __restrict__ h_outb,
                const ushort* __restrict__ wfO,
                const ushort* __restrict__ wfGh,
                const ushort* __restrict__ wfCh,
                const float* __restrict__ b_ode,
                const float* __restrict__ tsteps,
                const float* __restrict__ mask,
                int t)
{
    extern __shared__ ushort smem[];
    float*  smemf = (float*)smem;
    ushort* hbuf  = smem;
    ushort* obuf  = smem + 17408;
    ushort* rhbuf = smem;
    float*  ubuf  = smemf + 4352;
    float*  hode  = smemf + 15232;

    const int l  = blockIdx.x;
    const int rt = 2 * (l & 7) + ((l >> 3) & 1);
    const int b  = l >> 4;
    const int R  = rt * 2;
    const int tid = threadIdx.x;
    const int w = tid >> 6, lane = tid & 63, lr = lane & 15, lg = lane >> 4;
    const int bti = b * TT + (TT - 1 - t);

    const ushort* hbb = h_inb + (size_t)b * 1026 * 64;
    const float*  hb  = h_in  + (size_t)b * 65536;
    const ushort* axb = axc + (size_t)bti * 1024 * 192;

    // ---- hoisted Gx/Cx acc-init loads ----
    short4v gxr[2][4], cxr[2];
    {
        const int cq = w & 3, ph = w >> 2;
        #pragma unroll
        for (int i = 0; i < 2; ++i) {
            const int cog0 = (2 * cq + i) * 16 + lg * 4;
            #pragma unroll
            for (int j = 0; j < 4; ++j) {
                const int f = 4 * ph + j;
                const int y = R - 1 + (f >> 1);
                const int c = (f & 1) * 16 + lr;
                short4v g = (short4v)0;
                if ((unsigned)y < 32u)
                    g = *(const short4v*)(axb + ((size_t)(y * 32 + c)) * 192 + cog0);
                gxr[i][j] = g;
            }
        }
        const int cf = w & 3, ph2 = w >> 2;
        const int co0 = cf * 16 + lg * 4;
        #pragma unroll
        for (int j = 0; j < 2; ++j) {
            const int c = j * 16 + lr;
            const int pix = (R + (ph2 & 1)) * 32 + c;
            cxr[j] = *(const short4v*)(axb + (size_t)pix * 192 + 128 + co0);
        }
    }

    // ---- stage: hbuf rows R-3..R+4 (zero at t==0) ; obuf edge zero ----
    for (int i = tid; i < 2176; i += 512) {
        const int tr = i / 272, rem = i - tr * 272;
        const int hc = rem >> 3;
        const int y  = R - 3 + tr;
        short8 v = (short8)0;
        if (t != 0 && (unsigned)y < 32u && hc != 0 && hc != 33)
            v = *(const short8*)(hbb + ((size_t)(y * 32 + hc)) * 64 + (rem & 7) * 8);
        *(short8*)(hbuf + (size_t)i * 8) = v;
    }
    for (int i = tid; i < 1632; i += 512) {
        const int tr = i / 272, rem = i - tr * 272;
        const int hc = rem >> 3;
        const int y  = R - 2 + tr;
        if (hc == 0 || hc == 33 || (unsigned)y >= 32u)
            *(short8*)(obuf + (size_t)i * 8) = (short8)0;
    }
    __syncthreads();

    // ---- phase A: h_ode rows R-2..R+3 (K=64 over hbuf) ----
    {
        const int cb0 = (w & 1) * 2;
        const int pxg = w >> 1;
        f32x4 accA[2][3];
        #pragma unroll
        for (int i = 0; i < 2; ++i)
            #pragma unroll
            for (int j = 0; j < 3; ++j) accA[i][j] = 0;

        #pragma unroll
        for (int tap = 0; tap < 9; ++tap) {
            const int ky = tap / 3, kx = tap - ky * 3;
            #pragma unroll
            for (int kc = 0; kc < 2; ++kc) {
                short8 a0 = *(const short8*)(wfO + (size_t)(((tap * 4 + cb0 + 0) * 2 + kc) * 512) + lane * 8);
                short8 a1 = *(const short8*)(wfO + (size_t)(((tap * 4 + cb0 + 1) * 2 + kc) * 512) + lane * 8);
                #pragma unroll
                for (int j = 0; j < 3; ++j) {
                    const int p  = (3 * pxg + j) * 16 + lr;
                    const int tr = (p >> 5) + ky, hc = (p & 31) + kx;
                    short8 bf = *(const short8*)(hbuf + (tr * 34 + hc) * 64 + ((((kc << 2) + lg) ^ ((hc + 7) & 7)) << 3));
                    accA[0][j] = __builtin_amdgcn_mfma_f32_16x16x32_bf16(a0, bf, accA[0][j], 0, 0, 0);
                    accA[1][j] = __builtin_amdgcn_mfma_f32_16x16x32_bf16(a1, bf, accA[1][j], 0, 0, 0);
                }
            }
        }
        const float dt = (t == 0) ? -0.01f : (tsteps[TT - 1 - t] - tsteps[TT - t]);
        #pragma unroll
        for (int i = 0; i < 2; ++i) {
            #pragma unroll
            for (int j = 0; j < 3; ++j) {
                const int co0 = (cb0 + i) * 16 + lg * 4;
                const int p = (3 * pxg + j) * 16 + lr;
                const int orow = p >> 5, c = p & 31;
                const int y = R - 2 + orow;
                if ((unsigned)y < 32u) {
                    const int key = (((co0 >> 3) ^ (c & 7)) << 3) + (co0 & 7);
                    f32x4 h4;
                    if ((unsigned)(y - R) < 2u) {       // owned rows: exact fp32 chain
                        if (t == 0) {
                            h4 = 0;
                        } else {
                            h4 = *(const f32x4*)(hb + ((size_t)(y * 32 + c)) * 64 + co0);
                        }
                    } else {                             // halo rows: bf16 h from hbuf
                        short4v hv = *(const short4v*)(hbuf + ((orow + 1) * 34 + c + 1) * 64 + key);
                        #pragma unroll
                        for (int r = 0; r < 4; ++r) h4[r] = bf2f((ushort)hv[r]);
                    }
                    const f32x4 b4 = *(const f32x4*)(b_ode + co0);
                    f32x4 ho;
                    #pragma unroll
                    for (int r = 0; r < 4; ++r)
                        ho[r] = h4[r] + fast_tanh(accA[i][j][r] + b4[r]) * dt;
                    short4v s;
                    #pragma unroll
                    for (int r = 0; r < 4; ++r) s[r] = (short)f2bf(ho[r]);
                    *(short4v*)(obuf + (orow * 34 + c + 1) * 64 + key) = s;
                    if ((unsigned)(y - R) < 2u)
                        *(f32x4*)(hode + ((y - R) * 32 + c) * 64 + (((co0 >> 2) ^ (c & 15)) << 2)) = ho;
                }
            }
        }
    }
    __syncthreads();

    // rhbuf: zero halo cols + OOB rows (overlays dead hbuf)
    for (int i = tid; i < 1088; i += 512) {
        const int tr = i / 272, rem = i - tr * 272;
        const int hc = rem >> 3;
        const int y  = R - 1 + tr;
        if (hc == 0 || hc == 33 || (unsigned)y >= 32u)
            *(short8*)(rhbuf + (size_t)i * 8) = (short8)0;
    }

    // ---- phase B: gates rows R-1..R+2 (K=64 over obuf, acc init from Gx) ----
    {
        const int cq = w & 3, ph = w >> 2;
        f32x4 accB[2][4];
        #pragma unroll
        for (int i = 0; i < 2; ++i)
            #pragma unroll
            for (int j = 0; j < 4; ++j) {
                f32x4 g;
                #pragma unroll
                for (int r = 0; r < 4; ++r) g[r] = bf2f((ushort)gxr[i][j][r]);
                accB[i][j] = g;
            }

        #pragma unroll
        for (int tap = 0; tap < 9; ++tap) {
            const int ky = tap / 3, kx = tap - ky * 3;
            #pragma unroll
            for (int kc = 0; kc < 2; ++kc) {
                short8 a0 = *(const short8*)(wfGh + (size_t)(((tap * 8 + 2 * cq + 0) * 2 + kc) * 512) + lane * 8);
                short8 a1 = *(const short8*)(wfGh + (size_t)(((tap * 8 + 2 * cq + 1) * 2 + kc) * 512) + lane * 8);
                #pragma unroll
                for (int j = 0; j < 4; ++j) {
                    const int f  = 4 * ph + j;
                    const int tr = (f >> 1) + ky;
                    const int hc = (f & 1) * 16 + lr + kx;
                    short8 bf = *(const short8*)(obuf + (tr * 34 + hc) * 64 + ((((kc << 2) + lg) ^ ((hc + 7) & 7)) << 3));
                    accB[0][j] = __builtin_amdgcn_mfma_f32_16x16x32_bf16(a0, bf, accB[0][j], 0, 0, 0);
                    accB[1][j] = __builtin_amdgcn_mfma_f32_16x16x32_bf16(a1, bf, accB[1][j], 0, 0, 0);
                }
            }
        }
        #pragma unroll
        for (int i = 0; i < 2; ++i) {
            const int cog = (2 * cq + i) * 16 + lg * 4;
            #pragma unroll
            for (int j = 0; j < 4; ++j) {
                const int f = 4 * ph + j;
                const int y = R - 1 + (f >> 1);
                const int c = (f & 1) * 16 + lr;
                if (cq < 2) {
                    if ((unsigned)y < 32u) {
                        const int tro = (f >> 1) + 1;
                        const int key = (((cog >> 3) ^ (c & 7)) << 3) + (cog & 7);
                        short4v ho4 = *(const short4v*)(obuf + (tro * 34 + c + 1) * 64 + key);
                        short4v s;
                        #pragma unroll
                        for (int r = 0; r < 4; ++r)
                            s[r] = (short)f2bf(fast_sigmoid(accB[i][j][r]) * bf2f((ushort)ho4[r]));
                        *(short4v*)(rhbuf + ((f >> 1) * 34 + c + 1) * 64 + key) = s;
                    }
                } else if ((unsigned)(y - R) < 2u) {
                    const int cu = cog - 64;
                    f32x4 u;
                    #pragma unroll
                    for (int r = 0; r < 4; ++r)
                        u[r] = fast_sigmoid(accB[i][j][r]);
                    *(f32x4*)(ubuf + ((y - R) * 32 + c) * 64 + (((cu >> 2) ^ (c & 15)) << 2)) = u;
                }
            }
        }
    }
    __syncthreads();

    // ---- phase C: cand rows R..R+1 (K=64 over rhbuf, acc init from Cx) ; GRU update ----
    {
        const int cf = w & 3, ph2 = w >> 2;
        const int co0 = cf * 16 + lg * 4;
        f32x4 accC[2];
        #pragma unroll
        for (int j = 0; j < 2; ++j) {
            f32x4 g;
            #pragma unroll
            for (int r = 0; r < 4; ++r) g[r] = bf2f((ushort)cxr[j][r]);
            accC[j] = g;
        }

        #pragma unroll
        for (int tap = 0; tap < 9; ++tap) {
            const int ky = tap / 3, kx = tap - ky * 3;
            #pragma unroll
            for (int kc = 0; kc < 2; ++kc) {
                short8 a = *(const short8*)(wfCh + (size_t)(((tap * 4 + cf) * 2 + kc) * 512) + lane * 8);
                #pragma unroll
                for (int j = 0; j < 2; ++j) {
                    const int tr = ph2 + ky;
                    const int hc = j * 16 + lr + kx;
                    short8 bf = *(const short8*)(rhbuf + (tr * 34 + hc) * 64 + ((((kc << 2) + lg) ^ ((hc + 7) & 7)) << 3));
                    accC[j] = __builtin_amdgcn_mfma_f32_16x16x32_bf16(a, bf, accC[j], 0, 0, 0);
                }
            }
        }
        const float m = mask[b * TT + (TT - 1 - t)];
        const int y = R + ph2;
        #pragma unroll
        for (int j = 0; j < 2; ++j) {
            const int c = j * 16 + lr;
            const int pi = ph2 * 32 + c;
            const int sw = ((co0 >> 2) ^ (c & 15)) << 2;
            const f32x4 ho = *(const f32x4*)(hode + pi * 64 + sw);
            const f32x4 u  = *(const f32x4*)(ubuf + pi * 64 + sw);
            f32x4 o;
            short4v s;
            #pragma unroll
            for (int r = 0; r < 4; ++r) {
                const float cand = fast_tanh(accC[j][r]);
                o[r] = ho[r] + m * u[r] * (cand - ho[r]);
                s[r] = (short)f2bf(o[r]);
            }
            const int pix = y * 32 + c;
            *(f32x4*)(h_out + (size_t)b * 65536 + (size_t)pix * 64 + co0) = o;
            *(short4v*)(h_outb + ((size_t)b * 1026 + 1 + pix) * 64
                        + (((co0 >> 3) ^ (c & 7)) << 3) + (co0 & 7)) = s;
        }
    }
}

// Head: z = relu(W1 h + b1); z2 = W2 z + b2; out NCHW (mean, |std|)
__global__ __launch_bounds__(256)
void head_mfma(const float* __restrict__ h,
               const ushort* __restrict__ w1f, const float* __restrict__ b1,
               const ushort* __restrict__ w2f, const float* __restrict__ b2,
               float* __restrict__ outp)
{
    __shared__ ushort hlds[64 * 64];
    __shared__ ushort zlds[64 * 64];
    const int blk = blockIdx.x, b = blk >> 4, pixb = (blk & 15) * 64;
    const int tid = threadIdx.x, wv = tid >> 6, lane = tid & 63, lr = lane & 15, lg = lane >> 4;
    const float* hb = h + ((size_t)b * 1024 + pixb) * 64;

    for (int idx = tid; idx < 64 * 8; idx += 256) {
        const int c = idx & 7, px = idx >> 3;
        const float* p = hb + (size_t)px * 64 + c * 8;
        short8 v;
        #pragma unroll
        for (int e = 0; e < 8; ++e) v[e] = (short)f2bf(p[e]);
        *(short8*)(hlds + px * 64 + ((c ^ (px & 7)) << 3)) = v;
    }
    __syncthreads();

    f32x4 acc1[4]; acc1[0]=0; acc1[1]=0; acc1[2]=0; acc1[3]=0;
    #pragma unroll
    for (int kc = 0; kc < 2; ++kc) {
        short8 a = *(const short8*)(w1f + (((size_t)wv * 2 + kc) * 64 + lane) * 8);
        #pragma unroll
        for (int p = 0; p < 4; ++p) {
            const int hp = p * 16 + lr;
            short8 bf = *(const short8*)(hlds + hp * 64 + (((kc * 4 + lg) ^ (hp & 7)) << 3));
            acc1[p] = __builtin_amdgcn_mfma_f32_16x16x32_bf16(a, bf, acc1[p], 0, 0, 0);
        }
    }
    {
        const int co0 = wv * 16 + lg * 4;
        const f32x4 b4 = *(const f32x4*)(b1 + co0);
        #pragma unroll
        for (int p = 0; p < 4; ++p) {
            const int px = p * 16 + lr;
            short4v s;
            #pragma unroll
            for (int r = 0; r < 4; ++r)
                s[r] = (short)f2bf(fmaxf(acc1[p][r] + b4[r], 0.0f));
            *(short4v*)(zlds + px * 64 + (((co0 >> 3) ^ (px & 7)) << 3) + (co0 & 7)) = s;
        }
    }
    __syncthreads();

    f32x4 acc2[2][4];
    #pragma unroll
    for (int gi = 0; gi < 2; ++gi)
        #pragma unroll
        for (int p = 0; p < 4; ++p) acc2[gi][p] = 0;
    #pragma unroll
    for (int kc = 0; kc < 2; ++kc) {
        short8 a0 = *(const short8*)(w2f + ((((size_t)wv * 2 + 0) * 2 + kc) * 64 + lane) * 8);
        short8 a1 = *(const short8*)(w2f + ((((size_t)wv * 2 + 1) * 2 + kc) * 64 + lane) * 8);
        #pragma unroll
        for (int p = 0; p < 4; ++p) {
            const int hp = p * 16 + lr;
            short8 bf = *(const short8*)(zlds + hp * 64 + (((kc * 4 + lg) ^ (hp & 7)) << 3));
            acc2[0][p] = __builtin_amdgcn_mfma_f32_16x16x32_bf16(a0, bf, acc2[0][p], 0, 0, 0);
            acc2[1][p] = __builtin_amdgcn_mfma_f32_16x16x32_bf16(a1, bf, acc2[1][p], 0, 0, 0);
        }
    }
    #pragma unroll
    for (int gi = 0; gi < 2; ++gi) {
        const int co0 = wv * 32 + gi * 16 + lg * 4;
        const f32x4 b4 = *(const f32x4*)(b2 + co0);
        #pragma unroll
        for (int p = 0; p < 4; ++p) {
            const int px = pixb + p * 16 + lr;
            #pragma unroll
            for (int r = 0; r < 4; ++r) {
                const int co = co0 + r;
                const float v = acc2[gi][p][r] + b4[r];
                if (co < 64)
                    outp[((size_t)b * 64 + co) * 1024 + px] = v;
                else
                    outp[(size_t)BB * 64 * 1024 + ((size_t)b * 64 + (co - 64)) * 1024 + px] = fabsf(v);
            }
        }
    }
}

extern "C" void kernel_launch(void* const* d_in, const int* in_sizes, int n_in,
                              void* d_out, int out_size, void* d_ws, size_t ws_size,
                              hipStream_t stream)
{
    const float* xall    = (const float*)d_in[0];
    const float* tsteps  = (const float*)d_in[1];
    const float* mask    = (const float*)d_in[2];
    const float* w_gates = (const float*)d_in[3];
    const float* b_gates = (const float*)d_in[4];
    const float* w_can   = (const float*)d_in[5];
    const float* b_can   = (const float*)d_in[6];
    const float* w_ode   = (const float*)d_in[7];
    const float* b_ode   = (const float*)d_in[8];
    const float* w_t1    = (const float*)d_in[9];
    const float* b_t1    = (const float*)d_in[10];
    const float* w_t2    = (const float*)d_in[11];
    const float* b_t2    = (const float*)d_in[12];
    float* out = (float*)d_out;

    float*  h0   = (float*)d_ws;
    float*  h1   = h0 + (size_t)BB * 65536;
    ushort* h0b  = (ushort*)(h1 + (size_t)BB * 65536);
    ushort* h1b  = h0b + (size_t)BB * 1026 * 64;
    ushort* axc  = h1b + (size_t)BB * 1026 * 64;
    ushort* wfX  = axc + (size_t)256 * 1024 * 192;
    ushort* wfGh = wfX  + (size_t)216 * 512;
    ushort* wfCh = wfGh + (size_t)144 * 512;
    ushort* wfO  = wfCh + (size_t)72 * 512;
    ushort* wf1  = wfO  + (size_t)72 * 512;
    ushort* wf2  = wf1  + (size_t)8 * 512;

    pack_all<<<dim3(132), 256, 0, stream>>>(w_gates, w_can, w_ode, w_t1, w_t2,
                                            wfX, wfGh, wfCh, wfO, wf1, wf2);

    hipFuncSetAttribute(reinterpret_cast<const void*>(conv_x),
                        hipFuncAttributeMaxDynamicSharedMemorySize, 77056);
    conv_x<<<dim3(8, 256), 512, 77056, stream>>>(xall, wfX, b_gates, b_can, axc);

    hipFuncSetAttribute(reinterpret_cast<const void*>(fused_step),
                        hipFuncAttributeMaxDynamicSharedMemorySize, 77312);

    for (int t = 0; t < TT; ++t) {
        const float*  hin   = (t & 1) ? h1  : h0;
        float*        hout  = (t & 1) ? h0  : h1;
        const ushort* hinb  = (t & 1) ? h1b : h0b;
        ushort*       houtb = (t & 1) ? h0b : h1b;
        fused_step<<<dim3(256), 512, 77312, stream>>>(axc, hin, hinb, hout, houtb,
                                                      wfO, wfGh, wfCh,
                                                      b_ode, tsteps, mask, t);
    }
    head_mfma<<<dim3(256), 256, 0, stream>>>(h0, wf1, b_t1, wf2, b_t2, out);
}